// Round 6
// baseline (234.739 us; speedup 1.0000x reference)
//
#include <hip/hip_runtime.h>
#include <hip/hip_bf16.h>
#include <math.h>

#define D_MODEL 1024
#define SEQ     2048
#define BATCH   2
#define NHEAD   16
#define DKH     64
#define BH      (BATCH * NHEAD)   // 32

typedef unsigned short u16;
typedef unsigned int   u32;
typedef __bf16 bf16x8 __attribute__((ext_vector_type(8)));
typedef float  f32x4  __attribute__((ext_vector_type(4)));

#define MFMA16(a, b, c) __builtin_amdgcn_mfma_f32_16x16x32_bf16((a), (b), (c), 0, 0, 0)
#define AS1 __attribute__((address_space(1)))
#define AS3 __attribute__((address_space(3)))

// 1/(8*ln2): folded into Q so softmax is exp2(s) with no fma and no shift
#define QSCALE 0.18033688f

__device__ __forceinline__ u16 f2bf(float x) {
    u32 u = __float_as_uint(x);
    u += 0x7fffu + ((u >> 16) & 1u);   // RNE (finite data)
    return (u16)(u >> 16);
}
__device__ __forceinline__ float bf2f(u16 b) {
    return __uint_as_float(((u32)b) << 16);
}
// async global->LDS, 16B/lane; lds dest wave-uniform (lane*16 implicit)
__device__ __forceinline__ void gl16(const u16* g, void* lds) {
    __builtin_amdgcn_global_load_lds((const AS1 u32*)g, (AS3 u32*)lds, 16, 0, 0);
}

// ---------------------------------------------------------------------------
// Conversions, one launch:
//   blocks [0, 4096)    : x fp32 -> bf16 (hi only)
//   blocks [4096, 5120) : W [K][N] fp32 -> WT hi/lo bf16 [N][K] (4 matrices)
// ---------------------------------------------------------------------------
__global__ __launch_bounds__(256) void conv_all(
    const float* __restrict__ x, u16* __restrict__ Xh, int n4,
    const float* __restrict__ W0, const float* __restrict__ W1,
    const float* __restrict__ W2, const float* __restrict__ W3,
    u16* __restrict__ H0, u16* __restrict__ L0, u16* __restrict__ H1, u16* __restrict__ L1,
    u16* __restrict__ H2, u16* __restrict__ L2, u16* __restrict__ H3, u16* __restrict__ L3)
{
    const int t = threadIdx.x;
    if ((int)blockIdx.x < 4096) {
        int i = blockIdx.x * 256 + t;
        if (i >= n4) return;
        float4 v = reinterpret_cast<const float4*>(x)[i];
        uint2 H;
        H.x = f2bf(v.x) | ((u32)f2bf(v.y) << 16);
        H.y = f2bf(v.z) | ((u32)f2bf(v.w) << 16);
        reinterpret_cast<uint2*>(Xh)[i] = H;
        return;
    }
    int id = blockIdx.x - 4096;          // 0..1023
    int bx = id & 15, by = (id >> 4) & 15, bz = id >> 8;
    const float* W; u16 *Ht, *Lt;
    if (bz == 0)      { W = W0; Ht = H0; Lt = L0; }
    else if (bz == 1) { W = W1; Ht = H1; Lt = L1; }
    else if (bz == 2) { W = W2; Ht = H2; Lt = L2; }
    else              { W = W3; Ht = H3; Lt = L3; }

    __shared__ float T[64][65];
    const int n0 = bx * 64, k0 = by * 64;
    #pragma unroll
    for (int i = 0; i < 4; ++i) {
        int f = t + i * 256;
        int kr = f >> 4, ns = (f & 15) * 4;
        float4 v = *reinterpret_cast<const float4*>(&W[(size_t)(k0 + kr) * D_MODEL + n0 + ns]);
        T[kr][ns + 0] = v.x; T[kr][ns + 1] = v.y; T[kr][ns + 2] = v.z; T[kr][ns + 3] = v.w;
    }
    __syncthreads();
    #pragma unroll
    for (int i = 0; i < 4; ++i) {
        int f = t + i * 256;
        int nr = f >> 4, ks = (f & 15) * 4;
        u16 hh[4], ll[4];
        #pragma unroll
        for (int j = 0; j < 4; ++j) {
            float xv = T[ks + j][nr];
            u16 hb = f2bf(xv);
            hh[j] = hb;
            ll[j] = f2bf(xv - bf2f(hb));
        }
        uint2 H, L;
        H.x = hh[0] | ((u32)hh[1] << 16); H.y = hh[2] | ((u32)hh[3] << 16);
        L.x = ll[0] | ((u32)ll[1] << 16); L.y = ll[2] | ((u32)ll[3] << 16);
        size_t o = (size_t)(n0 + nr) * D_MODEL + k0 + ks;
        *reinterpret_cast<uint2*>(&Ht[o]) = H;
        *reinterpret_cast<uint2*>(&Lt[o]) = L;
    }
}

// ---------------------------------------------------------------------------
// Fused QKV GEMM, 2-term split: C = Ah @ (Bh+Bl)^T + bias.
// 512 threads (8 waves); 128x128 tile; wave tile 64x32 (2M x 4N).
// Structure (R5): hi weights + A staged in LDS (shared 8x / 2x across
// waves); LO weights read DIRECTLY global->VGPR (per-wave anyway; L1-resident
// 16KB/phase working set) -- cuts LDS reads 128->80KB/iter, staging 56->32KB.
// ONE barrier per K=32 iter: vmcnt(6) proves each wave's 4 staged chunks
// (A,Bqh,Bkh,Bvh) landed; after the barrier the 3 output phases flow with
// counted-vmcnt data waits only (no intra-iter barriers).
// Per-wave issue order/invariant (steady state, entry): outstanding =
// [A(i),qh(i),kh(i),vh(i),ql(i)x2] = 6.
// Q output pre-scaled by QSCALE (softmax fold). All outputs flat bf16.
// ---------------------------------------------------------------------------
__global__ __launch_bounds__(512, 2) void gemm_qkv(
    const u16* __restrict__ AhG,
    const u16* __restrict__ Bqh, const u16* __restrict__ Bql,
    const u16* __restrict__ Bkh, const u16* __restrict__ Bkl,
    const u16* __restrict__ Bvh, const u16* __restrict__ Bvl,
    const float* __restrict__ bq, const float* __restrict__ bk, const float* __restrict__ bv,
    u16* __restrict__ Qb, u16* __restrict__ Kb, u16* __restrict__ Vb)
{
    constexpr int K = D_MODEL, N = D_MODEL;
    __shared__ u16 LB[2][16384];   // per buf: A | Bqh | Bkh | Bvh (8KB each)

    const int tid  = threadIdx.x;
    const int wv   = tid >> 6;
    const int lane = tid & 63;
    const int quad = lane >> 4;
    const int l16  = lane & 15;
    const int wm   = wv & 1, wn = wv >> 1;   // wave tile 64 rows x 32 cols
    const int brow = blockIdx.y * 128, bcol = blockIdx.x * 128;

    // staging: 4 chunks per wave, one per array (cc = wv): j=0 A, 1 Bqh, 2 Bkh, 3 Bvh
    const u16* sp[4];
    int sldb[4];
    {
        int row  = wv * 16 + (lane >> 2);
        int gseg = (lane & 3) ^ ((lane >> 3) & 3);
        const u16* ps[4] = { AhG, Bqh, Bkh, Bvh };
        #pragma unroll
        for (int j = 0; j < 4; ++j) {
            int rbase = (j == 0) ? brow : bcol;
            sp[j]   = ps[j] + (size_t)(rbase + row) * K + gseg * 8;
            sldb[j] = j * 8192 + wv * 1024;
        }
    }

    int aro[4], bro[2];
    #pragma unroll
    for (int i = 0; i < 4; ++i) {
        int mr = wm * 64 + i * 16 + l16;
        aro[i] = mr * 64 + ((quad ^ ((mr >> 1) & 3)) * 16);
    }
    #pragma unroll
    for (int i = 0; i < 2; ++i) {
        int nr = wn * 32 + i * 16 + l16;
        bro[i] = nr * 64 + ((quad ^ ((nr >> 1) & 3)) * 16);
    }

    // lo-weight direct-load rows (per-lane): frag = 8 k-elems at k-octet `quad`
    const int r0 = bcol + wn * 32 + l16, r1 = r0 + 16;
    const int qo = quad * 8;

    f32x4 acc[3][4][2] = {};

    auto mm2 = [&](int m, bf16x8 (&ah)[4], bf16x8 bh0, bf16x8 bh1,
                   bf16x8 bl0, bf16x8 bl1) {
        __builtin_amdgcn_s_setprio(1);
        #pragma unroll
        for (int mi = 0; mi < 4; ++mi) {
            f32x4 c0 = acc[m][mi][0], c1 = acc[m][mi][1];
            c0 = MFMA16(ah[mi], bh0, c0);
            c1 = MFMA16(ah[mi], bh1, c1);
            c0 = MFMA16(ah[mi], bl0, c0);
            c1 = MFMA16(ah[mi], bl1, c1);
            acc[m][mi][0] = c0; acc[m][mi][1] = c1;
        }
        __builtin_amdgcn_s_setprio(0);
    };

    // prologue: stage iter 0 (order A,qh,kh,vh), prefetch ql(0)
    #pragma unroll
    for (int j = 0; j < 4; ++j)
        gl16(sp[j], (char*)LB[0] + sldb[j]);
    bf16x8 pql0 = *reinterpret_cast<const bf16x8*>(Bql + (size_t)r0 * K + qo);
    bf16x8 pql1 = *reinterpret_cast<const bf16x8*>(Bql + (size_t)r1 * K + qo);

    for (int it = 0; it < K / 32 - 1; ++it) {
        const int cur = it & 1, nx = cur ^ 1;
        const int k1 = (it + 1) * 32;
        const int kk = it * 32 + qo;

        // lo prefetch for this iter's K and V phases
        bf16x8 kl0 = *reinterpret_cast<const bf16x8*>(Bkl + (size_t)r0 * K + kk);
        bf16x8 kl1 = *reinterpret_cast<const bf16x8*>(Bkl + (size_t)r1 * K + kk);
        bf16x8 vl0 = *reinterpret_cast<const bf16x8*>(Bvl + (size_t)r0 * K + kk);
        bf16x8 vl1 = *reinterpret_cast<const bf16x8*>(Bvl + (size_t)r1 * K + kk);

        // single barrier: 4 oldest (this iter's staged chunks) proven done
        asm volatile("s_waitcnt vmcnt(6)" ::: "memory");
        __builtin_amdgcn_s_barrier();

        // ---- phase 0 : Q ----
        gl16(sp[0] + k1, (char*)LB[nx] + sldb[0]);
        gl16(sp[1] + k1, (char*)LB[nx] + sldb[1]);
        bf16x8 ah[4];
        #pragma unroll
        for (int i = 0; i < 4; ++i)
            ah[i] = *reinterpret_cast<const bf16x8*>((const char*)LB[cur] + aro[i]);
        bf16x8 bh0 = *reinterpret_cast<const bf16x8*>((const char*)LB[cur] + 8192 + bro[0]);
        bf16x8 bh1 = *reinterpret_cast<const bf16x8*>((const char*)LB[cur] + 8192 + bro[1]);
        asm volatile("s_waitcnt vmcnt(6)" ::: "memory");   // ql(i) ready
        mm2(0, ah, bh0, bh1, pql0, pql1);

        // ---- phase 1 : K ----
        gl16(sp[2] + k1, (char*)LB[nx] + sldb[2]);
        bh0 = *reinterpret_cast<const bf16x8*>((const char*)LB[cur] + 16384 + bro[0]);
        bh1 = *reinterpret_cast<const bf16x8*>((const char*)LB[cur] + 16384 + bro[1]);
        asm volatile("s_waitcnt vmcnt(5)" ::: "memory");   // kl(i) ready
        mm2(1, ah, bh0, bh1, kl0, kl1);

        // ---- phase 2 : V ----
        gl16(sp[3] + k1, (char*)LB[nx] + sldb[3]);
        bh0 = *reinterpret_cast<const bf16x8*>((const char*)LB[cur] + 24576 + bro[0]);
        bh1 = *reinterpret_cast<const bf16x8*>((const char*)LB[cur] + 24576 + bro[1]);
        asm volatile("s_waitcnt vmcnt(4)" ::: "memory");   // vl(i) ready
        mm2(2, ah, bh0, bh1, vl0, vl1);

        // prefetch ql(i+1) (newest -> next iter's invariant holds)
        pql0 = *reinterpret_cast<const bf16x8*>(Bql + (size_t)r0 * K + k1 + qo);
        pql1 = *reinterpret_cast<const bf16x8*>(Bql + (size_t)r1 * K + k1 + qo);
    }

    // ---- last iteration peeled: no prefetch; exact drain counts ----
    {
        const int it = K / 32 - 1;
        const int cur = it & 1;
        const int kk = it * 32 + qo;

        bf16x8 kl0 = *reinterpret_cast<const bf16x8*>(Bkl + (size_t)r0 * K + kk);
        bf16x8 kl1 = *reinterpret_cast<const bf16x8*>(Bkl + (size_t)r1 * K + kk);
        bf16x8 vl0 = *reinterpret_cast<const bf16x8*>(Bvl + (size_t)r0 * K + kk);
        bf16x8 vl1 = *reinterpret_cast<const bf16x8*>(Bvl + (size_t)r1 * K + kk);

        asm volatile("s_waitcnt vmcnt(6)" ::: "memory");
        __builtin_amdgcn_s_barrier();

        bf16x8 ah[4];
        #pragma unroll
        for (int i = 0; i < 4; ++i)
            ah[i] = *reinterpret_cast<const bf16x8*>((const char*)LB[cur] + aro[i]);
        bf16x8 bh0 = *reinterpret_cast<const bf16x8*>((const char*)LB[cur] + 8192 + bro[0]);
        bf16x8 bh1 = *reinterpret_cast<const bf16x8*>((const char*)LB[cur] + 8192 + bro[1]);
        asm volatile("s_waitcnt vmcnt(4)" ::: "memory");
        mm2(0, ah, bh0, bh1, pql0, pql1);

        bh0 = *reinterpret_cast<const bf16x8*>((const char*)LB[cur] + 16384 + bro[0]);
        bh1 = *reinterpret_cast<const bf16x8*>((const char*)LB[cur] + 16384 + bro[1]);
        asm volatile("s_waitcnt vmcnt(2)" ::: "memory");
        mm2(1, ah, bh0, bh1, kl0, kl1);

        bh0 = *reinterpret_cast<const bf16x8*>((const char*)LB[cur] + 24576 + bro[0]);
        bh1 = *reinterpret_cast<const bf16x8*>((const char*)LB[cur] + 24576 + bro[1]);
        asm volatile("s_waitcnt vmcnt(0)" ::: "memory");
        mm2(2, ah, bh0, bh1, vl0, vl1);
    }

    // epilogue: Q pre-scaled for exp2-softmax; all flat bf16
    #pragma unroll
    for (int m = 0; m < 3; ++m) {
        const float* bias = (m == 0) ? bq : (m == 1) ? bk : bv;
        u16* out = (m == 0) ? Qb : (m == 1) ? Kb : Vb;
        const float sc = (m == 0) ? QSCALE : 1.0f;
        #pragma unroll
        for (int mi = 0; mi < 4; ++mi) {
            #pragma unroll
            for (int ni = 0; ni < 2; ++ni) {
                int col = bcol + wn * 32 + ni * 16 + l16;
                float bvv = bias[col];
                #pragma unroll
                for (int r = 0; r < 4; ++r) {
                    int row = brow + wm * 64 + mi * 16 + quad * 4 + r;
                    out[(size_t)row * N + col] = f2bf((acc[m][mi][ni][r] + bvv) * sc);
                }
            }
        }
    }
}

// ---------------------------------------------------------------------------
// Out-proj GEMM, 2-term: out = Ctx @ (Woh+Wol)^T + bo, fp32 out.
// Same R5 structure: A + Bh staged (LDS 16KB/buf), Bl direct global->VGPR;
// one barrier + counted vmcnt per iter. Invariant: [A(i),Bh(i),bl(i)x2] = 4.
// ---------------------------------------------------------------------------
__global__ __launch_bounds__(512, 2) void gemm_oproj(
    const u16* __restrict__ AhG, const u16* __restrict__ Bh, const u16* __restrict__ Bl,
    const float* __restrict__ bias, float* __restrict__ Cf)
{
    constexpr int K = D_MODEL, N = D_MODEL;
    __shared__ u16 LB[2][8192];   // per buf: A | Bh (8KB each)

    const int tid  = threadIdx.x;
    const int wv   = tid >> 6;
    const int lane = tid & 63;
    const int quad = lane >> 4;
    const int l16  = lane & 15;
    const int wm   = wv & 1, wn = wv >> 1;   // wave tile 64 rows x 32 cols
    const int brow = blockIdx.y * 128, bcol = blockIdx.x * 128;

    const u16* sp[2];
    int sldb[2];
    {
        int row  = wv * 16 + (lane >> 2);
        int gseg = (lane & 3) ^ ((lane >> 3) & 3);
        sp[0]   = AhG + (size_t)(brow + row) * K + gseg * 8;
        sp[1]   = Bh  + (size_t)(bcol + row) * K + gseg * 8;
        sldb[0] = wv * 1024;
        sldb[1] = 8192 + wv * 1024;
    }

    int aro[4], bro[2];
    #pragma unroll
    for (int i = 0; i < 4; ++i) {
        int mr = wm * 64 + i * 16 + l16;
        aro[i] = mr * 64 + ((quad ^ ((mr >> 1) & 3)) * 16);
    }
    #pragma unroll
    for (int i = 0; i < 2; ++i) {
        int nr = wn * 32 + i * 16 + l16;
        bro[i] = nr * 64 + ((quad ^ ((nr >> 1) & 3)) * 16);
    }

    const int r0 = bcol + wn * 32 + l16, r1 = r0 + 16;
    const int qo = quad * 8;

    f32x4 acc[4][2] = {};

    // prologue
    gl16(sp[0], (char*)LB[0] + sldb[0]);
    gl16(sp[1], (char*)LB[0] + sldb[1]);
    bf16x8 pbl0 = *reinterpret_cast<const bf16x8*>(Bl + (size_t)r0 * K + qo);
    bf16x8 pbl1 = *reinterpret_cast<const bf16x8*>(Bl + (size_t)r1 * K + qo);

    for (int it = 0; it < K / 32 - 1; ++it) {
        const int cur = it & 1, nx = cur ^ 1;
        const int k1 = (it + 1) * 32;

        asm volatile("s_waitcnt vmcnt(2)" ::: "memory");   // A(i),Bh(i) landed
        __builtin_amdgcn_s_barrier();

        gl16(sp[0] + k1, (char*)LB[nx] + sldb[0]);
        gl16(sp[1] + k1, (char*)LB[nx] + sldb[1]);

        bf16x8 ah[4], bh0, bh1;
        #pragma unroll
        for (int i = 0; i < 4; ++i)
            ah[i] = *reinterpret_cast<const bf16x8*>((const char*)LB[cur] + aro[i]);
        bh0 = *reinterpret_cast<const bf16x8*>((const char*)LB[cur] + 8192 + bro[0]);
        bh1 = *reinterpret_cast<const bf16x8*>((const char*)LB[cur] + 8192 + bro[1]);

        asm volatile("s_waitcnt vmcnt(2)" ::: "memory");   // bl(i) ready
        __builtin_amdgcn_s_setprio(1);
        #pragma unroll
        for (int mi = 0; mi < 4; ++mi) {
            f32x4 c0 = acc[mi][0], c1 = acc[mi][1];
            c0 = MFMA16(ah[mi], bh0, c0);
            c1 = MFMA16(ah[mi], bh1, c1);
            c0 = MFMA16(ah[mi], pbl0, c0);
            c1 = MFMA16(ah[mi], pbl1, c1);
            acc[mi][0] = c0; acc[mi][1] = c1;
        }
        __builtin_amdgcn_s_setprio(0);

        pbl0 = *reinterpret_cast<const bf16x8*>(Bl + (size_t)r0 * K + k1 + qo);
        pbl1 = *reinterpret_cast<const bf16x8*>(Bl + (size_t)r1 * K + k1 + qo);
    }

    {   // peeled last iter
        const int cur = (K / 32 - 1) & 1;
        asm volatile("s_waitcnt vmcnt(2)" ::: "memory");
        __builtin_amdgcn_s_barrier();
        bf16x8 ah[4], bh0, bh1;
        #pragma unroll
        for (int i = 0; i < 4; ++i)
            ah[i] = *reinterpret_cast<const bf16x8*>((const char*)LB[cur] + aro[i]);
        bh0 = *reinterpret_cast<const bf16x8*>((const char*)LB[cur] + 8192 + bro[0]);
        bh1 = *reinterpret_cast<const bf16x8*>((const char*)LB[cur] + 8192 + bro[1]);
        asm volatile("s_waitcnt vmcnt(0)" ::: "memory");
        __builtin_amdgcn_s_setprio(1);
        #pragma unroll
        for (int mi = 0; mi < 4; ++mi) {
            f32x4 c0 = acc[mi][0], c1 = acc[mi][1];
            c0 = MFMA16(ah[mi], bh0, c0);
            c1 = MFMA16(ah[mi], bh1, c1);
            c0 = MFMA16(ah[mi], pbl0, c0);
            c1 = MFMA16(ah[mi], pbl1, c1);
            acc[mi][0] = c0; acc[mi][1] = c1;
        }
        __builtin_amdgcn_s_setprio(0);
    }

    #pragma unroll
    for (int mi = 0; mi < 4; ++mi) {
        #pragma unroll
        for (int ni = 0; ni < 2; ++ni) {
            int col = bcol + wn * 32 + ni * 16 + l16;
            float bvv = bias[col];
            #pragma unroll
            for (int r = 0; r < 4; ++r) {
                int row = brow + wm * 64 + mi * 16 + quad * 4 + r;
                Cf[(size_t)row * N + col] = acc[mi][ni][r] + bvv;
            }
        }
    }
}

// ---------------------------------------------------------------------------
// V bf16 flat [BH][SEQ][64] -> Vt bf16 [BH][64][SEQ], with k PERMUTED within
// each 64-tile: p(k=16*t4+l) = 4*l + t4. This matches attn's packed-b64 P
// store layout; PV contracts P and V positionally so both sides permute.
// ---------------------------------------------------------------------------
__global__ __launch_bounds__(256) void v_transpose(
    const u16* __restrict__ V, u16* __restrict__ Vt)
{
    __shared__ u16 T[64][72];
    const int bh = blockIdx.y, st = blockIdx.x;
    const u16* src = V + ((size_t)bh * SEQ + (size_t)st * 64) * 64;
    const int t = threadIdx.x;
    #pragma unroll
    for (int i = 0; i < 2; ++i) {
        int c  = t + i * 256;
        int s  = c >> 3;
        int d0 = (c & 7) * 8;
        uint4 v = reinterpret_cast<const uint4*>(src)[c];
        u16 e[8];
        e[0] = (u16)(v.x & 0xffff); e[1] = (u16)(v.x >> 16);
        e[2] = (u16)(v.y & 0xffff); e[3] = (u16)(v.y >> 16);
        e[4] = (u16)(v.z & 0xffff); e[5] = (u16)(v.z >> 16);
        e[6] = (u16)(v.w & 0xffff); e[7] = (u16)(v.w >> 16);
        #pragma unroll
        for (int j = 0; j < 8; ++j) T[d0 + j][s] = e[j];
    }
    __syncthreads();
    // permuted gather: dest positions 8g..8g+7 hold kv
    // [2g, 2g+16, 2g+32, 2g+48, 2g+1, 2g+17, 2g+33, 2g+49]
    const int d = t >> 2, seg = t & 3;
    u16* dst = Vt + (size_t)bh * 64 * SEQ + (size_t)d * SEQ + st * 64;
    #pragma unroll
    for (int gg = 0; gg < 2; ++gg) {
        int g = seg * 2 + gg;
        u32 r0 = *reinterpret_cast<const u32*>(&T[d][2 * g]);
        u32 r1 = *reinterpret_cast<const u32*>(&T[d][2 * g + 16]);
        u32 r2 = *reinterpret_cast<const u32*>(&T[d][2 * g + 32]);
        u32 r3 = *reinterpret_cast<const u32*>(&T[d][2 * g + 48]);
        uint4 w;
        w.x = (r0 & 0xffffu) | (r1 << 16);
        w.y = (r2 & 0xffffu) | (r3 << 16);
        w.z = (r0 >> 16) | (r1 & 0xffff0000u);
        w.w = (r2 >> 16) | (r3 & 0xffff0000u);
        *reinterpret_cast<uint4*>(&dst[8 * g]) = w;
    }
}

// ---------------------------------------------------------------------------
// MFMA flash attention, 512 threads (8 waves x 16 q-rows): 4 waves/SIMD for
// latency hiding. Q pre-scaled -> p = exp2(s); truncated-bf16 P;
// row sums via ones-MFMA on the SAME bf16 P fragments.
// P stored k-PERMUTED (p(16t4+l)=4l+t4) so each thread's 4 exp2 results for
// one row pack into ONE ds_write_b64. V's k order pre-permuted identically.
// T15 PV-lag pipeline (KVS triple-buffered) + T5 setprio.
// LDS 66 KB -> 2 blocks/CU. 1D grid (512), XCD swizzle bh = id&31.
// ---------------------------------------------------------------------------
__global__ __launch_bounds__(512, 4) void attn_mfma(
    const u16* __restrict__ Qb_g, const u16* __restrict__ Kb_g,
    const u16* __restrict__ Vt_g, u16* __restrict__ Ch_g)
{
    __shared__ u16 KVS[3][8192];   // per buf: Kb(8KB) | Vt(8KB)
    __shared__ u16 Pb [128 * 72];

    const int tid  = threadIdx.x;
    const int wv   = tid >> 6;          // 0..7
    const int lane = tid & 63;
    const int quad = lane >> 4;
    const int l16  = lane & 15;
    const int id   = blockIdx.x;
    const int bh   = id & 31;           // XCD = id%8 = bh%8
    const int qt   = id >> 5;           // 0..15
    const int qrow = wv * 16;           // wave's 16 q-rows

    const size_t qbase = ((size_t)bh * SEQ + (size_t)qt * 128) * 64;
    const size_t kbh   = (size_t)bh * SEQ * 64;
    const size_t vtbh  = (size_t)bh * 64 * SEQ;

    // ---- Q fragments: direct global -> VGPR (16 q-rows per wave) ----
    bf16x8 qf[2];
    #pragma unroll
    for (int ks = 0; ks < 2; ++ks) {
        size_t o = qbase + (size_t)(qrow + l16) * 64 + ks * 32 + quad * 8;
        qf[ks] = *reinterpret_cast<const bf16x8*>(Qb_g + o);
    }

    // K/V staging: 16 chunks of 1 KB (Kb 0-7, Vt 8-15); 2 per wave
    const u16* sp[2];
    size_t sstep[2];
    int sldb[2];
    #pragma unroll
    for (int j = 0; j < 2; ++j) {
        int c   = wv * 2 + j;            // 0..15
        int arr = c >> 3, cc = c & 7;
        int row = cc * 8 + (lane >> 3);
        int sg  = (lane & 7) ^ (row & 7);
        if (arr == 0) { sp[j] = Kb_g + kbh + (size_t)row * 64 + sg * 8;   sstep[j] = 4096; }
        else          { sp[j] = Vt_g + vtbh + (size_t)row * SEQ + sg * 8; sstep[j] = 64; }
        sldb[j] = arr * 8192 + cc * 1024;
    }

    int fro[4][2];
    #pragma unroll
    for (int t = 0; t < 4; ++t)
        #pragma unroll
        for (int ks = 0; ks < 2; ++ks)
            fro[t][ks] = (t * 16 + l16) * 128 + (((ks * 4 + quad) ^ (l16 & 7)) * 16);

    bf16x8 onesv;
    #pragma unroll
    for (int i = 0; i < 8; ++i) onesv[i] = (__bf16)1.0f;

    f32x4 oacc[4] = {};
    f32x4 lsum = {};

    // ---- pipeline stage helpers ----
    auto S_step = [&](int bufidx, f32x4 (&sacc)[4]) {
        const char* kb = (const char*)KVS[bufidx];
        #pragma unroll
        for (int t4 = 0; t4 < 4; ++t4) {
            bf16x8 kh0 = *reinterpret_cast<const bf16x8*>(kb + fro[t4][0]);
            bf16x8 kh1 = *reinterpret_cast<const bf16x8*>(kb + fro[t4][1]);
            f32x4 a = sacc[t4];
            a = MFMA16(qf[0], kh0, a);
            a = MFMA16(qf[1], kh1, a);
            sacc[t4] = a;
        }
    };

    auto PV_step = [&](int bufidx) {
        const char* vb = (const char*)KVS[bufidx] + 8192;
        bf16x8 bvf[4][2];
        #pragma unroll
        for (int dt = 0; dt < 4; ++dt) {
            bvf[dt][0] = *reinterpret_cast<const bf16x8*>(vb + fro[dt][0]);
            bvf[dt][1] = *reinterpret_cast<const bf16x8*>(vb + fro[dt][1]);
        }
        bf16x8 ap[2];
        #pragma unroll
        for (int ks = 0; ks < 2; ++ks)
            ap[ks] = *reinterpret_cast<const bf16x8*>(
                &Pb[(qrow + l16) * 72 + ks * 32 + quad * 8]);
        #pragma unroll
        for (int dt = 0; dt < 4; ++dt) {
            oacc[dt] = MFMA16(ap[0], bvf[dt][0], oacc[dt]);
            oacc[dt] = MFMA16(ap[1], bvf[dt][1], oacc[dt]);
        }
        lsum = MFMA16(ap[0], onesv, lsum);
        lsum = MFMA16(ap[1], onesv, lsum);
    };

    auto EXP2_step = [&](f32x4 (&sacc)[4]) {
        const int rowb = qrow + quad * 4;
        #pragma unroll
        for (int r = 0; r < 4; ++r) {
            u32 u0 = __float_as_uint(__builtin_amdgcn_exp2f(sacc[0][r]));
            u32 u1 = __float_as_uint(__builtin_amdgcn_exp2f(sacc[1][r]));
            u32 u2 = __float_as_uint(__builtin_amdgcn_exp2f(sacc[2][r]));
            u32 u3 = __float_as_uint(__builtin_amdgcn_exp2f(sacc[3][r]));
            // permuted pack: elements 4*l16 + {0,1,2,3} = t4 0..3 (truncated bf16)
            uint2 w;
            w.x = (u0 >> 16) | (u1 & 0xffff0000u);
            w.y = (u2 >> 16) | (u3 & 0xffff0000u);
            *reinterpret_cast<uint2*>(&Pb[(rowb + r) * 72 + l16 * 4]) = w;
        }
    };

    // ---- prologue: stage tile 0 ----
    #pragma unroll
    for (int j = 0; j < 2; ++j)
        gl16(sp[j], (char*)KVS[0] + sldb[j]);

    // ---- kt = 0 peeled (no PV yet) ----
    {
        __syncthreads();
        #pragma unroll
        for (int j = 0; j < 2; ++j)
            gl16(sp[j] + sstep[j], (char*)KVS[1] + sldb[j]);
        f32x4 sacc[4] = {};
        __builtin_amdgcn_s_setprio(1);
        S_step(0, sacc);
        __builtin_amdgcn_s_setprio(0);
        EXP2_step(sacc);
    }

    // ---- main loop: S(kt) || PV(kt-1), then exp2(kt) ----
    int cur = 1, prv = 0, nxt = 2;
    for (int kt = 1; kt < SEQ / 64; ++kt) {
        __syncthreads();
        if (kt + 1 < SEQ / 64) {
            #pragma unroll
            for (int j = 0; j < 2; ++j)
                gl16(sp[j] + (size_t)(kt + 1) * sstep[j], (char*)KVS[nxt] + sldb[j]);
        }

        f32x4 sacc[4] = {};
        __builtin_amdgcn_s_setprio(1);
        S_step(cur, sacc);
        PV_step(prv);            // reads Pb(kt-1) BEFORE exp2(kt) overwrites it
        __builtin_amdgcn_s_setprio(0);
        EXP2_step(sacc);

        prv = cur; cur = nxt; nxt = (nxt == 2) ? 0 : nxt + 1;
    }

    // ---- drain: PV on the last tile (V landed at last barrier; Pb same-wave)
    __builtin_amdgcn_s_setprio(1);
    PV_step(prv);                // prv == (SEQ/64 - 1) % 3
    __builtin_amdgcn_s_setprio(0);

    // ---- epilogue: normalize by lsum (C-layout rows match oacc), store ----
    u16* Oh = Ch_g + qbase;
    float inv[4];
    #pragma unroll
    for (int r = 0; r < 4; ++r) inv[r] = 1.0f / lsum[r];
    #pragma unroll
    for (int dt = 0; dt < 4; ++dt)
        #pragma unroll
        for (int r = 0; r < 4; ++r) {
            int row = qrow + quad * 4 + r;
            Oh[(size_t)row * 64 + dt * 16 + l16] = f2bf(oacc[dt][r] * inv[r]);
        }
}

// ---------------------------------------------------------------------------
extern "C" void kernel_launch(void* const* d_in, const int* in_sizes, int n_in,
                              void* d_out, int out_size, void* d_ws, size_t ws_size,
                              hipStream_t stream)
{
    const float* x  = (const float*)d_in[0];
    const float* Wq = (const float*)d_in[1];
    const float* bq = (const float*)d_in[2];
    const float* Wk = (const float*)d_in[3];
    const float* bk = (const float*)d_in[4];
    const float* Wv = (const float*)d_in[5];
    const float* bv = (const float*)d_in[6];
    const float* Wo = (const float*)d_in[7];
    const float* bo = (const float*)d_in[8];
    float* out = (float*)d_out;

    const int M = BATCH * SEQ;        // 4096
    const int N = D_MODEL;            // 1024
    const size_t NE = (size_t)M * N;  // 4,194,304
    const size_t NW = (size_t)N * N;  // 1,048,576

    u16* w16 = (u16*)d_ws;
    u16* Xh   = w16;
    u16* Qb   = Xh   + NE;
    u16* Kb   = Qb   + NE;
    u16* Vb   = Kb   + NE;
    u16* Vtb  = Vb   + NE;
    u16* Ctxh = Vtb  + NE;
    u16* WTqh = Ctxh + NE;
    u16* WTql = WTqh + NW;
    u16* WTkh = WTql + NW;
    u16* WTkl = WTkh + NW;
    u16* WTvh = WTkl + NW;
    u16* WTvl = WTvh + NW;
    u16* WToh = WTvl + NW;
    u16* WTol = WToh + NW;

    // conversions (single launch)
    conv_all<<<dim3(4096 + 1024), dim3(256), 0, stream>>>(
        x, Xh, (int)(NE / 4),
        Wq, Wk, Wv, Wo, WTqh, WTql, WTkh, WTkl, WTvh, WTvl, WToh, WTol);

    // fused QKV projection (hi staged / lo direct, 1-barrier counted-vmcnt)
    gemm_qkv<<<dim3(N / 128, M / 128), dim3(512), 0, stream>>>(
        Xh, WTqh, WTql, WTkh, WTkl, WTvh, WTvl, bq, bk, bv, Qb, Kb, Vb);

    // transpose V per contiguous reshape slab (k permuted to match packed P)
    v_transpose<<<dim3(SEQ / 64, BH), dim3(256), 0, stream>>>(Vb, Vtb);

    // attention (512 threads, 4 waves/SIMD; packed-b64 P; T15 PV-lag)
    attn_mfma<<<dim3((SEQ / 128) * BH), dim3(512), 0, stream>>>(Qb, Kb, Vtb, Ctxh);

    // output projection (hi staged / lo direct, 1-barrier counted-vmcnt)
    gemm_oproj<<<dim3(N / 128, M / 128), dim3(512), 0, stream>>>(
        Ctxh, WToh, WTol, bo, out);
}

// Round 7
// 208.597 us; speedup vs baseline: 1.1253x; 1.1253x over previous
//
#include <hip/hip_runtime.h>
#include <hip/hip_bf16.h>
#include <math.h>

#define D_MODEL 1024
#define SEQ     2048
#define BATCH   2
#define NHEAD   16
#define DKH     64
#define BH      (BATCH * NHEAD)   // 32

typedef unsigned short u16;
typedef unsigned int   u32;
typedef __bf16 bf16x8 __attribute__((ext_vector_type(8)));
typedef float  f32x4  __attribute__((ext_vector_type(4)));

#define MFMA16(a, b, c) __builtin_amdgcn_mfma_f32_16x16x32_bf16((a), (b), (c), 0, 0, 0)
#define AS1 __attribute__((address_space(1)))
#define AS3 __attribute__((address_space(3)))

// 1/(8*ln2): folded into Q so softmax is exp2(s) with no fma and no shift
#define QSCALE 0.18033688f

__device__ __forceinline__ u16 f2bf(float x) {
    u32 u = __float_as_uint(x);
    u += 0x7fffu + ((u >> 16) & 1u);   // RNE (finite data)
    return (u16)(u >> 16);
}
__device__ __forceinline__ float bf2f(u16 b) {
    return __uint_as_float(((u32)b) << 16);
}
// async global->LDS, 16B/lane; lds dest wave-uniform (lane*16 implicit)
__device__ __forceinline__ void gl16(const u16* g, void* lds) {
    __builtin_amdgcn_global_load_lds((const AS1 u32*)g, (AS3 u32*)lds, 16, 0, 0);
}

// ---------------------------------------------------------------------------
// Conversions, one launch:
//   blocks [0, 4096)    : x fp32 -> bf16 (hi only)
//   blocks [4096, 5120) : W [K][N] fp32 -> WT hi/lo bf16 [N][K] (4 matrices)
// ---------------------------------------------------------------------------
__global__ __launch_bounds__(256) void conv_all(
    const float* __restrict__ x, u16* __restrict__ Xh, int n4,
    const float* __restrict__ W0, const float* __restrict__ W1,
    const float* __restrict__ W2, const float* __restrict__ W3,
    u16* __restrict__ H0, u16* __restrict__ L0, u16* __restrict__ H1, u16* __restrict__ L1,
    u16* __restrict__ H2, u16* __restrict__ L2, u16* __restrict__ H3, u16* __restrict__ L3)
{
    const int t = threadIdx.x;
    if ((int)blockIdx.x < 4096) {
        int i = blockIdx.x * 256 + t;
        if (i >= n4) return;
        float4 v = reinterpret_cast<const float4*>(x)[i];
        uint2 H;
        H.x = f2bf(v.x) | ((u32)f2bf(v.y) << 16);
        H.y = f2bf(v.z) | ((u32)f2bf(v.w) << 16);
        reinterpret_cast<uint2*>(Xh)[i] = H;
        return;
    }
    int id = blockIdx.x - 4096;          // 0..1023
    int bx = id & 15, by = (id >> 4) & 15, bz = id >> 8;
    const float* W; u16 *Ht, *Lt;
    if (bz == 0)      { W = W0; Ht = H0; Lt = L0; }
    else if (bz == 1) { W = W1; Ht = H1; Lt = L1; }
    else if (bz == 2) { W = W2; Ht = H2; Lt = L2; }
    else              { W = W3; Ht = H3; Lt = L3; }

    __shared__ float T[64][65];
    const int n0 = bx * 64, k0 = by * 64;
    #pragma unroll
    for (int i = 0; i < 4; ++i) {
        int f = t + i * 256;
        int kr = f >> 4, ns = (f & 15) * 4;
        float4 v = *reinterpret_cast<const float4*>(&W[(size_t)(k0 + kr) * D_MODEL + n0 + ns]);
        T[kr][ns + 0] = v.x; T[kr][ns + 1] = v.y; T[kr][ns + 2] = v.z; T[kr][ns + 3] = v.w;
    }
    __syncthreads();
    #pragma unroll
    for (int i = 0; i < 4; ++i) {
        int f = t + i * 256;
        int nr = f >> 4, ks = (f & 15) * 4;
        u16 hh[4], ll[4];
        #pragma unroll
        for (int j = 0; j < 4; ++j) {
            float xv = T[ks + j][nr];
            u16 hb = f2bf(xv);
            hh[j] = hb;
            ll[j] = f2bf(xv - bf2f(hb));
        }
        uint2 H, L;
        H.x = hh[0] | ((u32)hh[1] << 16); H.y = hh[2] | ((u32)hh[3] << 16);
        L.x = ll[0] | ((u32)ll[1] << 16); L.y = ll[2] | ((u32)ll[3] << 16);
        size_t o = (size_t)(n0 + nr) * D_MODEL + k0 + ks;
        *reinterpret_cast<uint2*>(&Ht[o]) = H;
        *reinterpret_cast<uint2*>(&Lt[o]) = L;
    }
}

// ---------------------------------------------------------------------------
// Fused QKV GEMM, 2-term split: C = Ah @ (Bh+Bl)^T + bias.
// 512 threads (8 waves); 128x128 tile; wave tile 64x32 (2M x 4N).
// T3+T4 phase pipeline: 3 phases per K=32 step (one per output Q/K/V), raw
// s_barrier + counted vmcnt (4/5/5 steady; 4/2/0 in the peeled last iter).
// ALL arrays LDS-staged (R6 lesson: per-lane fragment loads from row-major
// weights at 2KB stride are uncoalesced 16-lines/load -- never bypass LDS).
// T5 setprio around each 16-MFMA cluster.
// Q output pre-scaled by QSCALE (softmax fold). All outputs flat bf16.
// ---------------------------------------------------------------------------
__global__ __launch_bounds__(512, 2) void gemm_qkv(
    const u16* __restrict__ AhG,
    const u16* __restrict__ Bqh, const u16* __restrict__ Bql,
    const u16* __restrict__ Bkh, const u16* __restrict__ Bkl,
    const u16* __restrict__ Bvh, const u16* __restrict__ Bvl,
    const float* __restrict__ bq, const float* __restrict__ bk, const float* __restrict__ bv,
    u16* __restrict__ Qb, u16* __restrict__ Kb, u16* __restrict__ Vb)
{
    constexpr int K = D_MODEL, N = D_MODEL;
    __shared__ u16 LB[2][28672];   // per buf: A | Bqh | Bql | Bkh | Bkl | Bvh | Bvl (8KB each)

    const int tid  = threadIdx.x;
    const int wv   = tid >> 6;
    const int lane = tid & 63;
    const int quad = lane >> 4;
    const int l16  = lane & 15;
    const int wm   = wv & 1, wn = wv >> 1;   // wave tile 64 rows x 32 cols
    const int brow = blockIdx.y * 128, bcol = blockIdx.x * 128;

    // staging: chunks grouped by phase. j=0..2 -> phase0 (arrays 0,1,2),
    // j=3..4 -> phase1 (arrays 3,4), j=5..6 -> phase2 (arrays 5,6).
    const u16* sp[7];
    int sldb[7];
    #pragma unroll
    for (int j = 0; j < 7; ++j) {
        int c = (j < 3) ? (wv * 3 + j)
              : (j < 5) ? (24 + wv * 2 + (j - 3))
                        : (40 + wv * 2 + (j - 5));
        int a = c >> 3, cc = c & 7;
        int row = cc * 16 + (lane >> 2);
        int gseg = (lane & 3) ^ ((lane >> 3) & 3);
        const u16* p;
        if (a == 0)      p = AhG;
        else if (a == 1) p = Bqh;
        else if (a == 2) p = Bql;
        else if (a == 3) p = Bkh;
        else if (a == 4) p = Bkl;
        else if (a == 5) p = Bvh;
        else             p = Bvl;
        int rbase = (a == 0) ? brow : bcol;
        sp[j]   = p + (size_t)(rbase + row) * K + gseg * 8;
        sldb[j] = a * 8192 + cc * 1024;
    }

    int aro[4], bro[2];
    #pragma unroll
    for (int i = 0; i < 4; ++i) {
        int mr = wm * 64 + i * 16 + l16;
        aro[i] = mr * 64 + ((quad ^ ((mr >> 1) & 3)) * 16);
    }
    #pragma unroll
    for (int i = 0; i < 2; ++i) {
        int nr = wn * 32 + i * 16 + l16;
        bro[i] = nr * 64 + ((quad ^ ((nr >> 1) & 3)) * 16);
    }

    f32x4 acc[3][4][2] = {};

    auto rdB = [&](int cur, int m, bf16x8 (&bh)[2], bf16x8 (&bl)[2]) {
        const int bbh = (1 + 2 * m) * 8192, bbl = (2 + 2 * m) * 8192;
        #pragma unroll
        for (int i = 0; i < 2; ++i) {
            bh[i] = *reinterpret_cast<const bf16x8*>((const char*)LB[cur] + bbh + bro[i]);
            bl[i] = *reinterpret_cast<const bf16x8*>((const char*)LB[cur] + bbl + bro[i]);
        }
    };
    auto mm = [&](int m, bf16x8 (&ah)[4], bf16x8 (&bh)[2], bf16x8 (&bl)[2]) {
        __builtin_amdgcn_s_setprio(1);
        #pragma unroll
        for (int mi = 0; mi < 4; ++mi)
            #pragma unroll
            for (int ni = 0; ni < 2; ++ni) {
                f32x4 c = acc[m][mi][ni];
                c = MFMA16(ah[mi], bh[ni], c);
                c = MFMA16(ah[mi], bl[ni], c);
                acc[m][mi][ni] = c;
            }
        __builtin_amdgcn_s_setprio(0);
    };

    // prologue: issue iter-0 loads in phase order (vmcnt counting relies on it)
    #pragma unroll
    for (int j = 0; j < 7; ++j)
        gl16(sp[j], (char*)LB[0] + sldb[j]);

    for (int it = 0; it < K / 32 - 1; ++it) {
        const int cur = it & 1, nx = cur ^ 1;
        const int k1 = (it + 1) * 32;
        bf16x8 ah[4], bh[2], bl[2];

        // ---- phase 0 : Q ---- (oldest 3 = this iter's A,Bqh,Bql chunks)
        asm volatile("s_waitcnt vmcnt(4)" ::: "memory");
        __builtin_amdgcn_s_barrier();
        #pragma unroll
        for (int i = 0; i < 4; ++i)
            ah[i] = *reinterpret_cast<const bf16x8*>((const char*)LB[cur] + aro[i]);
        rdB(cur, 0, bh, bl);
        gl16(sp[0] + k1, (char*)LB[nx] + sldb[0]);
        gl16(sp[1] + k1, (char*)LB[nx] + sldb[1]);
        gl16(sp[2] + k1, (char*)LB[nx] + sldb[2]);
        mm(0, ah, bh, bl);

        // ---- phase 1 : K ---- (oldest 2 = this iter's Bkh,Bkl)
        asm volatile("s_waitcnt vmcnt(5)" ::: "memory");
        __builtin_amdgcn_s_barrier();
        rdB(cur, 1, bh, bl);
        gl16(sp[3] + k1, (char*)LB[nx] + sldb[3]);
        gl16(sp[4] + k1, (char*)LB[nx] + sldb[4]);
        mm(1, ah, bh, bl);

        // ---- phase 2 : V ---- (oldest 2 = this iter's Bvh,Bvl)
        asm volatile("s_waitcnt vmcnt(5)" ::: "memory");
        __builtin_amdgcn_s_barrier();
        rdB(cur, 2, bh, bl);
        gl16(sp[5] + k1, (char*)LB[nx] + sldb[5]);
        gl16(sp[6] + k1, (char*)LB[nx] + sldb[6]);
        mm(2, ah, bh, bl);
    }

    // ---- last iteration peeled: no prefetch; exact drain counts ----
    {
        const int cur = (K / 32 - 1) & 1;
        bf16x8 ah[4], bh[2], bl[2];

        asm volatile("s_waitcnt vmcnt(4)" ::: "memory");
        __builtin_amdgcn_s_barrier();
        #pragma unroll
        for (int i = 0; i < 4; ++i)
            ah[i] = *reinterpret_cast<const bf16x8*>((const char*)LB[cur] + aro[i]);
        rdB(cur, 0, bh, bl);
        mm(0, ah, bh, bl);

        asm volatile("s_waitcnt vmcnt(2)" ::: "memory");
        __builtin_amdgcn_s_barrier();
        rdB(cur, 1, bh, bl);
        mm(1, ah, bh, bl);

        asm volatile("s_waitcnt vmcnt(0)" ::: "memory");
        __builtin_amdgcn_s_barrier();
        rdB(cur, 2, bh, bl);
        mm(2, ah, bh, bl);
    }

    // epilogue: Q pre-scaled for exp2-softmax; all flat bf16
    #pragma unroll
    for (int m = 0; m < 3; ++m) {
        const float* bias = (m == 0) ? bq : (m == 1) ? bk : bv;
        u16* out = (m == 0) ? Qb : (m == 1) ? Kb : Vb;
        const float sc = (m == 0) ? QSCALE : 1.0f;
        #pragma unroll
        for (int mi = 0; mi < 4; ++mi) {
            #pragma unroll
            for (int ni = 0; ni < 2; ++ni) {
                int col = bcol + wn * 32 + ni * 16 + l16;
                float bvv = bias[col];
                #pragma unroll
                for (int r = 0; r < 4; ++r) {
                    int row = brow + wm * 64 + mi * 16 + quad * 4 + r;
                    out[(size_t)row * N + col] = f2bf((acc[m][mi][ni][r] + bvv) * sc);
                }
            }
        }
    }
}

// ---------------------------------------------------------------------------
// Out-proj GEMM, 2-term: out = Ctx @ (Woh+Wol)^T + bo, fp32 out.
// NEW (R7): same counted-vmcnt phase structure as gemm_qkv, 2 phases per
// K=32 iter: phase0 = {A,Bh} staged chunks + hi-MFMA cluster, phase1 = {Bl}
// + lo-MFMA cluster. Steady waits vmcnt(1)/vmcnt(2); peeled last iter 1/0.
// All arrays LDS-staged (R6 lesson). Wave tile 64x32 (2M x 4N).
// ---------------------------------------------------------------------------
__global__ __launch_bounds__(512, 2) void gemm_oproj(
    const u16* __restrict__ AhG, const u16* __restrict__ Bh, const u16* __restrict__ Bl,
    const float* __restrict__ bias, float* __restrict__ Cf)
{
    constexpr int K = D_MODEL, N = D_MODEL;
    __shared__ u16 LB[2][12288];   // per buf: A | Bh | Bl (8KB each)

    const int tid  = threadIdx.x;
    const int wv   = tid >> 6;
    const int lane = tid & 63;
    const int quad = lane >> 4;
    const int l16  = lane & 15;
    const int wm   = wv & 1, wn = wv >> 1;   // wave tile 64 rows x 32 cols
    const int brow = blockIdx.y * 128, bcol = blockIdx.x * 128;

    // chunks: j=0 A (phase0), j=1 Bh (phase0), j=2 Bl (phase1); cc = wv
    const u16* sp[3];
    int sldb[3];
    {
        int row  = wv * 16 + (lane >> 2);
        int gseg = (lane & 3) ^ ((lane >> 3) & 3);
        sp[0]   = AhG + (size_t)(brow + row) * K + gseg * 8;
        sp[1]   = Bh  + (size_t)(bcol + row) * K + gseg * 8;
        sp[2]   = Bl  + (size_t)(bcol + row) * K + gseg * 8;
        sldb[0] = wv * 1024;
        sldb[1] = 8192 + wv * 1024;
        sldb[2] = 16384 + wv * 1024;
    }

    int aro[4], bro[2];
    #pragma unroll
    for (int i = 0; i < 4; ++i) {
        int mr = wm * 64 + i * 16 + l16;
        aro[i] = mr * 64 + ((quad ^ ((mr >> 1) & 3)) * 16);
    }
    #pragma unroll
    for (int i = 0; i < 2; ++i) {
        int nr = wn * 32 + i * 16 + l16;
        bro[i] = nr * 64 + ((quad ^ ((nr >> 1) & 3)) * 16);
    }

    f32x4 acc[4][2] = {};

    auto mmc = [&](bf16x8 (&ah)[4], bf16x8 b0, bf16x8 b1) {
        __builtin_amdgcn_s_setprio(1);
        #pragma unroll
        for (int mi = 0; mi < 4; ++mi) {
            f32x4 c0 = acc[mi][0], c1 = acc[mi][1];
            c0 = MFMA16(ah[mi], b0, c0);
            c1 = MFMA16(ah[mi], b1, c1);
            acc[mi][0] = c0; acc[mi][1] = c1;
        }
        __builtin_amdgcn_s_setprio(0);
    };

    // prologue: issue iter-0 loads in phase order (A, Bh, Bl)
    #pragma unroll
    for (int j = 0; j < 3; ++j)
        gl16(sp[j], (char*)LB[0] + sldb[j]);

    for (int it = 0; it < K / 32 - 1; ++it) {
        const int cur = it & 1, nx = cur ^ 1;
        const int k1 = (it + 1) * 32;
        bf16x8 ah[4], b0, b1;

        // ---- phase 0 : hi ---- (oldest 2 = this iter's A,Bh)
        asm volatile("s_waitcnt vmcnt(1)" ::: "memory");
        __builtin_amdgcn_s_barrier();
        #pragma unroll
        for (int i = 0; i < 4; ++i)
            ah[i] = *reinterpret_cast<const bf16x8*>((const char*)LB[cur] + aro[i]);
        b0 = *reinterpret_cast<const bf16x8*>((const char*)LB[cur] + 8192 + bro[0]);
        b1 = *reinterpret_cast<const bf16x8*>((const char*)LB[cur] + 8192 + bro[1]);
        gl16(sp[0] + k1, (char*)LB[nx] + sldb[0]);
        gl16(sp[1] + k1, (char*)LB[nx] + sldb[1]);
        mmc(ah, b0, b1);

        // ---- phase 1 : lo ---- (oldest 1 = this iter's Bl)
        asm volatile("s_waitcnt vmcnt(2)" ::: "memory");
        __builtin_amdgcn_s_barrier();
        b0 = *reinterpret_cast<const bf16x8*>((const char*)LB[cur] + 16384 + bro[0]);
        b1 = *reinterpret_cast<const bf16x8*>((const char*)LB[cur] + 16384 + bro[1]);
        gl16(sp[2] + k1, (char*)LB[nx] + sldb[2]);
        mmc(ah, b0, b1);
    }

    // ---- last iteration peeled: no prefetch; exact drain counts ----
    {
        const int cur = (K / 32 - 1) & 1;
        bf16x8 ah[4], b0, b1;

        asm volatile("s_waitcnt vmcnt(1)" ::: "memory");
        __builtin_amdgcn_s_barrier();
        #pragma unroll
        for (int i = 0; i < 4; ++i)
            ah[i] = *reinterpret_cast<const bf16x8*>((const char*)LB[cur] + aro[i]);
        b0 = *reinterpret_cast<const bf16x8*>((const char*)LB[cur] + 8192 + bro[0]);
        b1 = *reinterpret_cast<const bf16x8*>((const char*)LB[cur] + 8192 + bro[1]);
        mmc(ah, b0, b1);

        asm volatile("s_waitcnt vmcnt(0)" ::: "memory");
        __builtin_amdgcn_s_barrier();
        b0 = *reinterpret_cast<const bf16x8*>((const char*)LB[cur] + 16384 + bro[0]);
        b1 = *reinterpret_cast<const bf16x8*>((const char*)LB[cur] + 16384 + bro[1]);
        mmc(ah, b0, b1);
    }

    #pragma unroll
    for (int mi = 0; mi < 4; ++mi) {
        #pragma unroll
        for (int ni = 0; ni < 2; ++ni) {
            int col = bcol + wn * 32 + ni * 16 + l16;
            float bvv = bias[col];
            #pragma unroll
            for (int r = 0; r < 4; ++r) {
                int row = brow + wm * 64 + mi * 16 + quad * 4 + r;
                Cf[(size_t)row * N + col] = acc[mi][ni][r] + bvv;
            }
        }
    }
}

// ---------------------------------------------------------------------------
// V bf16 flat [BH][SEQ][64] -> Vt bf16 [BH][64][SEQ], with k PERMUTED within
// each 64-tile: p(k=16*t4+l) = 4*l + t4. This matches attn's packed-b64 P
// store layout; PV contracts P and V positionally so both sides permute.
// ---------------------------------------------------------------------------
__global__ __launch_bounds__(256) void v_transpose(
    const u16* __restrict__ V, u16* __restrict__ Vt)
{
    __shared__ u16 T[64][72];
    const int bh = blockIdx.y, st = blockIdx.x;
    const u16* src = V + ((size_t)bh * SEQ + (size_t)st * 64) * 64;
    const int t = threadIdx.x;
    #pragma unroll
    for (int i = 0; i < 2; ++i) {
        int c  = t + i * 256;
        int s  = c >> 3;
        int d0 = (c & 7) * 8;
        uint4 v = reinterpret_cast<const uint4*>(src)[c];
        u16 e[8];
        e[0] = (u16)(v.x & 0xffff); e[1] = (u16)(v.x >> 16);
        e[2] = (u16)(v.y & 0xffff); e[3] = (u16)(v.y >> 16);
        e[4] = (u16)(v.z & 0xffff); e[5] = (u16)(v.z >> 16);
        e[6] = (u16)(v.w & 0xffff); e[7] = (u16)(v.w >> 16);
        #pragma unroll
        for (int j = 0; j < 8; ++j) T[d0 + j][s] = e[j];
    }
    __syncthreads();
    // permuted gather: dest positions 8g..8g+7 hold kv
    // [2g, 2g+16, 2g+32, 2g+48, 2g+1, 2g+17, 2g+33, 2g+49]
    const int d = t >> 2, seg = t & 3;
    u16* dst = Vt + (size_t)bh * 64 * SEQ + (size_t)d * SEQ + st * 64;
    #pragma unroll
    for (int gg = 0; gg < 2; ++gg) {
        int g = seg * 2 + gg;
        u32 r0 = *reinterpret_cast<const u32*>(&T[d][2 * g]);
        u32 r1 = *reinterpret_cast<const u32*>(&T[d][2 * g + 16]);
        u32 r2 = *reinterpret_cast<const u32*>(&T[d][2 * g + 32]);
        u32 r3 = *reinterpret_cast<const u32*>(&T[d][2 * g + 48]);
        uint4 w;
        w.x = (r0 & 0xffffu) | (r1 << 16);
        w.y = (r2 & 0xffffu) | (r3 << 16);
        w.z = (r0 >> 16) | (r1 & 0xffff0000u);
        w.w = (r2 >> 16) | (r3 & 0xffff0000u);
        *reinterpret_cast<uint4*>(&dst[8 * g]) = w;
    }
}

// ---------------------------------------------------------------------------
// MFMA flash attention, 512 threads (8 waves x 16 q-rows): 4 waves/SIMD for
// latency hiding. Q pre-scaled -> p = exp2(s); truncated-bf16 P;
// row sums via ones-MFMA on the SAME bf16 P fragments.
// P stored k-PERMUTED (p(16t4+l)=4l+t4) so each thread's 4 exp2 results for
// one row pack into ONE ds_write_b64. V's k order pre-permuted identically.
// T15 PV-lag pipeline (KVS triple-buffered) + T5 setprio.
// LDS 66 KB -> 2 blocks/CU. 1D grid (512), XCD swizzle bh = id&31.
// ---------------------------------------------------------------------------
__global__ __launch_bounds__(512, 4) void attn_mfma(
    const u16* __restrict__ Qb_g, const u16* __restrict__ Kb_g,
    const u16* __restrict__ Vt_g, u16* __restrict__ Ch_g)
{
    __shared__ u16 KVS[3][8192];   // per buf: Kb(8KB) | Vt(8KB)
    __shared__ u16 Pb [128 * 72];

    const int tid  = threadIdx.x;
    const int wv   = tid >> 6;          // 0..7
    const int lane = tid & 63;
    const int quad = lane >> 4;
    const int l16  = lane & 15;
    const int id   = blockIdx.x;
    const int bh   = id & 31;           // XCD = id%8 = bh%8
    const int qt   = id >> 5;           // 0..15
    const int qrow = wv * 16;           // wave's 16 q-rows

    const size_t qbase = ((size_t)bh * SEQ + (size_t)qt * 128) * 64;
    const size_t kbh   = (size_t)bh * SEQ * 64;
    const size_t vtbh  = (size_t)bh * 64 * SEQ;

    // ---- Q fragments: direct global -> VGPR (16 q-rows per wave) ----
    bf16x8 qf[2];
    #pragma unroll
    for (int ks = 0; ks < 2; ++ks) {
        size_t o = qbase + (size_t)(qrow + l16) * 64 + ks * 32 + quad * 8;
        qf[ks] = *reinterpret_cast<const bf16x8*>(Qb_g + o);
    }

    // K/V staging: 16 chunks of 1 KB (Kb 0-7, Vt 8-15); 2 per wave
    const u16* sp[2];
    size_t sstep[2];
    int sldb[2];
    #pragma unroll
    for (int j = 0; j < 2; ++j) {
        int c   = wv * 2 + j;            // 0..15
        int arr = c >> 3, cc = c & 7;
        int row = cc * 8 + (lane >> 3);
        int sg  = (lane & 7) ^ (row & 7);
        if (arr == 0) { sp[j] = Kb_g + kbh + (size_t)row * 64 + sg * 8;   sstep[j] = 4096; }
        else          { sp[j] = Vt_g + vtbh + (size_t)row * SEQ + sg * 8; sstep[j] = 64; }
        sldb[j] = arr * 8192 + cc * 1024;
    }

    int fro[4][2];
    #pragma unroll
    for (int t = 0; t < 4; ++t)
        #pragma unroll
        for (int ks = 0; ks < 2; ++ks)
            fro[t][ks] = (t * 16 + l16) * 128 + (((ks * 4 + quad) ^ (l16 & 7)) * 16);

    bf16x8 onesv;
    #pragma unroll
    for (int i = 0; i < 8; ++i) onesv[i] = (__bf16)1.0f;

    f32x4 oacc[4] = {};
    f32x4 lsum = {};

    // ---- pipeline stage helpers ----
    auto S_step = [&](int bufidx, f32x4 (&sacc)[4]) {
        const char* kb = (const char*)KVS[bufidx];
        #pragma unroll
        for (int t4 = 0; t4 < 4; ++t4) {
            bf16x8 kh0 = *reinterpret_cast<const bf16x8*>(kb + fro[t4][0]);
            bf16x8 kh1 = *reinterpret_cast<const bf16x8*>(kb + fro[t4][1]);
            f32x4 a = sacc[t4];
            a = MFMA16(qf[0], kh0, a);
            a = MFMA16(qf[1], kh1, a);
            sacc[t4] = a;
        }
    };

    auto PV_step = [&](int bufidx) {
        const char* vb = (const char*)KVS[bufidx] + 8192;
        bf16x8 bvf[4][2];
        #pragma unroll
        for (int dt = 0; dt < 4; ++dt) {
            bvf[dt][0] = *reinterpret_cast<const bf16x8*>(vb + fro[dt][0]);
            bvf[dt][1] = *reinterpret_cast<const bf16x8*>(vb + fro[dt][1]);
        }
        bf16x8 ap[2];
        #pragma unroll
        for (int ks = 0; ks < 2; ++ks)
            ap[ks] = *reinterpret_cast<const bf16x8*>(
                &Pb[(qrow + l16) * 72 + ks * 32 + quad * 8]);
        #pragma unroll
        for (int dt = 0; dt < 4; ++dt) {
            oacc[dt] = MFMA16(ap[0], bvf[dt][0], oacc[dt]);
            oacc[dt] = MFMA16(ap[1], bvf[dt][1], oacc[dt]);
        }
        lsum = MFMA16(ap[0], onesv, lsum);
        lsum = MFMA16(ap[1], onesv, lsum);
    };

    auto EXP2_step = [&](f32x4 (&sacc)[4]) {
        const int rowb = qrow + quad * 4;
        #pragma unroll
        for (int r = 0; r < 4; ++r) {
            u32 u0 = __float_as_uint(__builtin_amdgcn_exp2f(sacc[0][r]));
            u32 u1 = __float_as_uint(__builtin_amdgcn_exp2f(sacc[1][r]));
            u32 u2 = __float_as_uint(__builtin_amdgcn_exp2f(sacc[2][r]));
            u32 u3 = __float_as_uint(__builtin_amdgcn_exp2f(sacc[3][r]));
            // permuted pack: elements 4*l16 + {0,1,2,3} = t4 0..3 (truncated bf16)
            uint2 w;
            w.x = (u0 >> 16) | (u1 & 0xffff0000u);
            w.y = (u2 >> 16) | (u3 & 0xffff0000u);
            *reinterpret_cast<uint2*>(&Pb[(rowb + r) * 72 + l16 * 4]) = w;
        }
    };

    // ---- prologue: stage tile 0 ----
    #pragma unroll
    for (int j = 0; j < 2; ++j)
        gl16(sp[j], (char*)KVS[0] + sldb[j]);

    // ---- kt = 0 peeled (no PV yet) ----
    {
        __syncthreads();
        #pragma unroll
        for (int j = 0; j < 2; ++j)
            gl16(sp[j] + sstep[j], (char*)KVS[1] + sldb[j]);
        f32x4 sacc[4] = {};
        __builtin_amdgcn_s_setprio(1);
        S_step(0, sacc);
        __builtin_amdgcn_s_setprio(0);
        EXP2_step(sacc);
    }

    // ---- main loop: S(kt) || PV(kt-1), then exp2(kt) ----
    int cur = 1, prv = 0, nxt = 2;
    for (int kt = 1; kt < SEQ / 64; ++kt) {
        __syncthreads();
        if (kt + 1 < SEQ / 64) {
            #pragma unroll
            for (int j = 0; j < 2; ++j)
                gl16(sp[j] + (size_t)(kt + 1) * sstep[j], (char*)KVS[nxt] + sldb[j]);
        }

        f32x4 sacc[4] = {};
        __builtin_amdgcn_s_setprio(1);
        S_step(cur, sacc);
        PV_step(prv);            // reads Pb(kt-1) BEFORE exp2(kt) overwrites it
        __builtin_amdgcn_s_setprio(0);
        EXP2_step(sacc);

        prv = cur; cur = nxt; nxt = (nxt == 2) ? 0 : nxt + 1;
    }

    // ---- drain: PV on the last tile (V landed at last barrier; Pb same-wave)
    __builtin_amdgcn_s_setprio(1);
    PV_step(prv);                // prv == (SEQ/64 - 1) % 3
    __builtin_amdgcn_s_setprio(0);

    // ---- epilogue: normalize by lsum (C-layout rows match oacc), store ----
    u16* Oh = Ch_g + qbase;
    float inv[4];
    #pragma unroll
    for (int r = 0; r < 4; ++r) inv[r] = 1.0f / lsum[r];
    #pragma unroll
    for (int dt = 0; dt < 4; ++dt)
        #pragma unroll
        for (int r = 0; r < 4; ++r) {
            int row = qrow + quad * 4 + r;
            Oh[(size_t)row * 64 + dt * 16 + l16] = f2bf(oacc[dt][r] * inv[r]);
        }
}

// ---------------------------------------------------------------------------
extern "C" void kernel_launch(void* const* d_in, const int* in_sizes, int n_in,
                              void* d_out, int out_size, void* d_ws, size_t ws_size,
                              hipStream_t stream)
{
    const float* x  = (const float*)d_in[0];
    const float* Wq = (const float*)d_in[1];
    const float* bq = (const float*)d_in[2];
    const float* Wk = (const float*)d_in[3];
    const float* bk = (const float*)d_in[4];
    const float* Wv = (const float*)d_in[5];
    const float* bv = (const float*)d_in[6];
    const float* Wo = (const float*)d_in[7];
    const float* bo = (const float*)d_in[8];
    float* out = (float*)d_out;

    const int M = BATCH * SEQ;        // 4096
    const int N = D_MODEL;            // 1024
    const size_t NE = (size_t)M * N;  // 4,194,304
    const size_t NW = (size_t)N * N;  // 1,048,576

    u16* w16 = (u16*)d_ws;
    u16* Xh   = w16;
    u16* Qb   = Xh   + NE;
    u16* Kb   = Qb   + NE;
    u16* Vb   = Kb   + NE;
    u16* Vtb  = Vb   + NE;
    u16* Ctxh = Vtb  + NE;
    u16* WTqh = Ctxh + NE;
    u16* WTql = WTqh + NW;
    u16* WTkh = WTql + NW;
    u16* WTkl = WTkh + NW;
    u16* WTvh = WTkl + NW;
    u16* WTvl = WTvh + NW;
    u16* WToh = WTvl + NW;
    u16* WTol = WToh + NW;

    // conversions (single launch)
    conv_all<<<dim3(4096 + 1024), dim3(256), 0, stream>>>(
        x, Xh, (int)(NE / 4),
        Wq, Wk, Wv, Wo, WTqh, WTql, WTkh, WTkl, WTvh, WTvl, WToh, WTol);

    // fused QKV projection (2-term, 3-phase counted-vmcnt pipeline)
    gemm_qkv<<<dim3(N / 128, M / 128), dim3(512), 0, stream>>>(
        Xh, WTqh, WTql, WTkh, WTkl, WTvh, WTvl, bq, bk, bv, Qb, Kb, Vb);

    // transpose V per contiguous reshape slab (k permuted to match packed P)
    v_transpose<<<dim3(SEQ / 64, BH), dim3(256), 0, stream>>>(Vb, Vtb);

    // attention (512 threads, 4 waves/SIMD; packed-b64 P; T15 PV-lag)
    attn_mfma<<<dim3((SEQ / 128) * BH), dim3(512), 0, stream>>>(Qb, Kb, Vtb, Ctxh);

    // output projection (2-term, 2-phase counted-vmcnt pipeline)
    gemm_oproj<<<dim3(N / 128, M / 128), dim3(512), 0, stream>>>(
        Ctxh, WToh, WTol, bo, out);
}

// Round 9
// 208.469 us; speedup vs baseline: 1.1260x; 1.0006x over previous
//
#include <hip/hip_runtime.h>
#include <hip/hip_bf16.h>
#include <math.h>

#define D_MODEL 1024
#define SEQ     2048
#define BATCH   2
#define NHEAD   16
#define DKH     64
#define BH      (BATCH * NHEAD)   // 32

typedef unsigned short u16;
typedef unsigned int   u32;
typedef __bf16 bf16x8 __attribute__((ext_vector_type(8)));
typedef float  f32x4  __attribute__((ext_vector_type(4)));

#define MFMA16(a, b, c) __builtin_amdgcn_mfma_f32_16x16x32_bf16((a), (b), (c), 0, 0, 0)
#define AS1 __attribute__((address_space(1)))
#define AS3 __attribute__((address_space(3)))

// 1/(8*ln2): folded into Q so softmax is exp2(s) with no fma and no shift
#define QSCALE 0.18033688f

__device__ __forceinline__ u16 f2bf(float x) {
    u32 u = __float_as_uint(x);
    u += 0x7fffu + ((u >> 16) & 1u);   // RNE (finite data)
    return (u16)(u >> 16);
}
__device__ __forceinline__ float bf2f(u16 b) {
    return __uint_as_float(((u32)b) << 16);
}
// async global->LDS, 16B/lane; lds dest wave-uniform (lane*16 implicit)
__device__ __forceinline__ void gl16(const u16* g, void* lds) {
    __builtin_amdgcn_global_load_lds((const AS1 u32*)g, (AS3 u32*)lds, 16, 0, 0);
}

// ---------------------------------------------------------------------------
// Conversions, one launch:
//   blocks [0, 4096)    : x fp32 -> bf16 (hi only)
//   blocks [4096, 5120) : W [K][N] fp32 -> WT hi/lo bf16 [N][K] (4 matrices)
// ---------------------------------------------------------------------------
__global__ __launch_bounds__(256) void conv_all(
    const float* __restrict__ x, u16* __restrict__ Xh, int n4,
    const float* __restrict__ W0, const float* __restrict__ W1,
    const float* __restrict__ W2, const float* __restrict__ W3,
    u16* __restrict__ H0, u16* __restrict__ L0, u16* __restrict__ H1, u16* __restrict__ L1,
    u16* __restrict__ H2, u16* __restrict__ L2, u16* __restrict__ H3, u16* __restrict__ L3)
{
    const int t = threadIdx.x;
    if ((int)blockIdx.x < 4096) {
        int i = blockIdx.x * 256 + t;
        if (i >= n4) return;
        float4 v = reinterpret_cast<const float4*>(x)[i];
        uint2 H;
        H.x = f2bf(v.x) | ((u32)f2bf(v.y) << 16);
        H.y = f2bf(v.z) | ((u32)f2bf(v.w) << 16);
        reinterpret_cast<uint2*>(Xh)[i] = H;
        return;
    }
    int id = blockIdx.x - 4096;          // 0..1023
    int bx = id & 15, by = (id >> 4) & 15, bz = id >> 8;
    const float* W; u16 *Ht, *Lt;
    if (bz == 0)      { W = W0; Ht = H0; Lt = L0; }
    else if (bz == 1) { W = W1; Ht = H1; Lt = L1; }
    else if (bz == 2) { W = W2; Ht = H2; Lt = L2; }
    else              { W = W3; Ht = H3; Lt = L3; }

    __shared__ float T[64][65];
    const int n0 = bx * 64, k0 = by * 64;
    #pragma unroll
    for (int i = 0; i < 4; ++i) {
        int f = t + i * 256;
        int kr = f >> 4, ns = (f & 15) * 4;
        float4 v = *reinterpret_cast<const float4*>(&W[(size_t)(k0 + kr) * D_MODEL + n0 + ns]);
        T[kr][ns + 0] = v.x; T[kr][ns + 1] = v.y; T[kr][ns + 2] = v.z; T[kr][ns + 3] = v.w;
    }
    __syncthreads();
    #pragma unroll
    for (int i = 0; i < 4; ++i) {
        int f = t + i * 256;
        int nr = f >> 4, ks = (f & 15) * 4;
        u16 hh[4], ll[4];
        #pragma unroll
        for (int j = 0; j < 4; ++j) {
            float xv = T[ks + j][nr];
            u16 hb = f2bf(xv);
            hh[j] = hb;
            ll[j] = f2bf(xv - bf2f(hb));
        }
        uint2 H, L;
        H.x = hh[0] | ((u32)hh[1] << 16); H.y = hh[2] | ((u32)hh[3] << 16);
        L.x = ll[0] | ((u32)ll[1] << 16); L.y = ll[2] | ((u32)ll[3] << 16);
        size_t o = (size_t)(n0 + nr) * D_MODEL + k0 + ks;
        *reinterpret_cast<uint2*>(&Ht[o]) = H;
        *reinterpret_cast<uint2*>(&Lt[o]) = L;
    }
}

// ---------------------------------------------------------------------------
// Fused QKV GEMM, 2-term split: C = Ah @ (Bh+Bl)^T + bias.
// R8: 128x64 tile, 256 threads (4 waves, wave tile 64x32), LDS 64KB total
// -> 2 BLOCKS/CU: two independent barrier domains overlap (m97 recipe).
// 3-phase counted-vmcnt: per wave 8 chunks/iter (ph0: 4 = A/Bqh/Bql,
// ph1: 2 = Bkh/Bkl, ph2: 2 = Bvh/Bvl); steady waits vmcnt(4)/(6)/(6);
// peeled last iter 4/2/0. All arrays LDS-staged (R6 lesson).
// Q output pre-scaled by QSCALE (softmax fold). All outputs flat bf16.
// ---------------------------------------------------------------------------
__global__ __launch_bounds__(256, 2) void gemm_qkv(
    const u16* __restrict__ AhG,
    const u16* __restrict__ Bqh, const u16* __restrict__ Bql,
    const u16* __restrict__ Bkh, const u16* __restrict__ Bkl,
    const u16* __restrict__ Bvh, const u16* __restrict__ Bvl,
    const float* __restrict__ bq, const float* __restrict__ bk, const float* __restrict__ bv,
    u16* __restrict__ Qb, u16* __restrict__ Kb, u16* __restrict__ Vb)
{
    constexpr int K = D_MODEL, N = D_MODEL;
    __shared__ u16 LB[2][16384];   // per buf 32KB: A(8KB) | Bqh|Bql|Bkh|Bkl|Bvh|Bvl (4KB each)

    const int tid  = threadIdx.x;
    const int wv   = tid >> 6;          // 0..3
    const int lane = tid & 63;
    const int quad = lane >> 4;
    const int l16  = lane & 15;
    const int wm   = wv & 1, wn = wv >> 1;   // wave tile 64 rows x 32 cols
    const int brow = blockIdx.y * 128, bcol = blockIdx.x * 64;

    // 8 staging chunks per wave: j=0..3 phase0, j=4..5 phase1, j=6..7 phase2
    const u16* ptrs[7] = { AhG, Bqh, Bql, Bkh, Bkl, Bvh, Bvl };
    const int abase[7] = { 0, 8192, 12288, 16384, 20480, 24576, 28672 };  // byte offs, sum=32KB
    const u16* sp[8];
    int sldb[8];
    #pragma unroll
    for (int j = 0; j < 8; ++j) {
        int a, cc;
        if (j < 4) {                      // ph0: A(8 chunks) + Bqh(4) + Bql(4)
            int c = wv * 4 + j;           // 0..15
            if (c < 8) { a = 0; cc = c; }
            else       { a = (c < 12) ? 1 : 2; cc = c & 3; }
        } else if (j < 6) {               // ph1: Bkh(4) + Bkl(4)
            int c = wv * 2 + (j - 4);     // 0..7
            a = 3 + (c >> 2); cc = c & 3;
        } else {                          // ph2: Bvh(4) + Bvl(4)
            int c = wv * 2 + (j - 6);     // 0..7
            a = 5 + (c >> 2); cc = c & 3;
        }
        int row  = cc * 16 + (lane >> 2);
        int gseg = (lane & 3) ^ ((lane >> 3) & 3);
        int rbase = (a == 0) ? brow : bcol;
        sp[j]   = ptrs[a] + (size_t)(rbase + row) * K + gseg * 8;
        sldb[j] = abase[a] + cc * 1024;
    }

    int aro[4], bro[2];
    #pragma unroll
    for (int i = 0; i < 4; ++i) {
        int mr = wm * 64 + i * 16 + l16;
        aro[i] = mr * 64 + ((quad ^ ((mr >> 1) & 3)) * 16);
    }
    #pragma unroll
    for (int i = 0; i < 2; ++i) {
        int nr = wn * 32 + i * 16 + l16;
        bro[i] = nr * 64 + ((quad ^ ((nr >> 1) & 3)) * 16);
    }

    f32x4 acc[3][4][2] = {};

    auto rdB = [&](int cur, int m, bf16x8 (&bh)[2], bf16x8 (&bl)[2]) {
        const int bbh = abase[1 + 2 * m], bbl = abase[2 + 2 * m];
        #pragma unroll
        for (int i = 0; i < 2; ++i) {
            bh[i] = *reinterpret_cast<const bf16x8*>((const char*)LB[cur] + bbh + bro[i]);
            bl[i] = *reinterpret_cast<const bf16x8*>((const char*)LB[cur] + bbl + bro[i]);
        }
    };
    auto mm = [&](int m, bf16x8 (&ah)[4], bf16x8 (&bh)[2], bf16x8 (&bl)[2]) {
        __builtin_amdgcn_s_setprio(1);
        #pragma unroll
        for (int mi = 0; mi < 4; ++mi)
            #pragma unroll
            for (int ni = 0; ni < 2; ++ni) {
                f32x4 c = acc[m][mi][ni];
                c = MFMA16(ah[mi], bh[ni], c);
                c = MFMA16(ah[mi], bl[ni], c);
                acc[m][mi][ni] = c;
            }
        __builtin_amdgcn_s_setprio(0);
    };

    // prologue: issue iter-0 loads in phase order (vmcnt counting relies on it)
    #pragma unroll
    for (int j = 0; j < 8; ++j)
        gl16(sp[j], (char*)LB[0] + sldb[j]);

    for (int it = 0; it < K / 32 - 1; ++it) {
        const int cur = it & 1, nx = cur ^ 1;
        const int k1 = (it + 1) * 32;
        bf16x8 ah[4], bh[2], bl[2];

        // ---- phase 0 : Q ---- (oldest 4 = this iter's ph0 chunks)
        asm volatile("s_waitcnt vmcnt(4)" ::: "memory");
        __builtin_amdgcn_s_barrier();
        #pragma unroll
        for (int i = 0; i < 4; ++i)
            ah[i] = *reinterpret_cast<const bf16x8*>((const char*)LB[cur] + aro[i]);
        rdB(cur, 0, bh, bl);
        gl16(sp[0] + k1, (char*)LB[nx] + sldb[0]);
        gl16(sp[1] + k1, (char*)LB[nx] + sldb[1]);
        gl16(sp[2] + k1, (char*)LB[nx] + sldb[2]);
        gl16(sp[3] + k1, (char*)LB[nx] + sldb[3]);
        mm(0, ah, bh, bl);

        // ---- phase 1 : K ---- (oldest 2 = this iter's ph1 chunks)
        asm volatile("s_waitcnt vmcnt(6)" ::: "memory");
        __builtin_amdgcn_s_barrier();
        rdB(cur, 1, bh, bl);
        gl16(sp[4] + k1, (char*)LB[nx] + sldb[4]);
        gl16(sp[5] + k1, (char*)LB[nx] + sldb[5]);
        mm(1, ah, bh, bl);

        // ---- phase 2 : V ---- (oldest 2 = this iter's ph2 chunks)
        asm volatile("s_waitcnt vmcnt(6)" ::: "memory");
        __builtin_amdgcn_s_barrier();
        rdB(cur, 2, bh, bl);
        gl16(sp[6] + k1, (char*)LB[nx] + sldb[6]);
        gl16(sp[7] + k1, (char*)LB[nx] + sldb[7]);
        mm(2, ah, bh, bl);
    }

    // ---- last iteration peeled: no prefetch; exact drain counts ----
    {
        const int cur = (K / 32 - 1) & 1;
        bf16x8 ah[4], bh[2], bl[2];

        asm volatile("s_waitcnt vmcnt(4)" ::: "memory");
        __builtin_amdgcn_s_barrier();
        #pragma unroll
        for (int i = 0; i < 4; ++i)
            ah[i] = *reinterpret_cast<const bf16x8*>((const char*)LB[cur] + aro[i]);
        rdB(cur, 0, bh, bl);
        mm(0, ah, bh, bl);

        asm volatile("s_waitcnt vmcnt(2)" ::: "memory");
        __builtin_amdgcn_s_barrier();
        rdB(cur, 1, bh, bl);
        mm(1, ah, bh, bl);

        asm volatile("s_waitcnt vmcnt(0)" ::: "memory");
        __builtin_amdgcn_s_barrier();
        rdB(cur, 2, bh, bl);
        mm(2, ah, bh, bl);
    }

    // epilogue: Q pre-scaled for exp2-softmax; all flat bf16
    #pragma unroll
    for (int m = 0; m < 3; ++m) {
        const float* bias = (m == 0) ? bq : (m == 1) ? bk : bv;
        u16* out = (m == 0) ? Qb : (m == 1) ? Kb : Vb;
        const float sc = (m == 0) ? QSCALE : 1.0f;
        #pragma unroll
        for (int mi = 0; mi < 4; ++mi) {
            #pragma unroll
            for (int ni = 0; ni < 2; ++ni) {
                int col = bcol + wn * 32 + ni * 16 + l16;
                float bvv = bias[col];
                #pragma unroll
                for (int r = 0; r < 4; ++r) {
                    int row = brow + wm * 64 + mi * 16 + quad * 4 + r;
                    out[(size_t)row * N + col] = f2bf((acc[m][mi][ni][r] + bvv) * sc);
                }
            }
        }
    }
}

// ---------------------------------------------------------------------------
// Out-proj GEMM, 2-term: out = Ctx @ (Woh+Wol)^T + bo, fp32 out.
// R8: 128x64 tile, 256 threads (4 waves), LDS 32KB total -> 2+ blocks/CU.
// 2-phase counted-vmcnt: per wave 4 chunks/iter (ph0: 3 = A+Bh, ph1: 1 = Bl);
// steady waits vmcnt(1)/(3); peeled last iter 1/0.
// R9 FIX: abase re-derived for the 16KB buffer: A@0(8KB), Bh@8192, Bl@12288
// (R8 inherited R7's 24KB-layout offsets -> Bh/Bl staged into the other
// buffer's A region and OOB LDS -> absmax 0.145).
// ---------------------------------------------------------------------------
__global__ __launch_bounds__(256, 2) void gemm_oproj(
    const u16* __restrict__ AhG, const u16* __restrict__ Bh, const u16* __restrict__ Bl,
    const float* __restrict__ bias, float* __restrict__ Cf)
{
    constexpr int K = D_MODEL, N = D_MODEL;
    __shared__ u16 LB[2][8192];   // per buf 16KB: A(8KB) | Bh(4KB) | Bl(4KB)

    const int tid  = threadIdx.x;
    const int wv   = tid >> 6;          // 0..3
    const int lane = tid & 63;
    const int quad = lane >> 4;
    const int l16  = lane & 15;
    const int wm   = wv & 1, wn = wv >> 1;   // wave tile 64 rows x 32 cols
    const int brow = blockIdx.y * 128, bcol = blockIdx.x * 64;

    // 4 staging chunks per wave: j=0..2 phase0 (A 8 + Bh 4), j=3 phase1 (Bl)
    const u16* ptrs[3] = { AhG, Bh, Bl };
    const int abase[3] = { 0, 8192, 12288 };   // byte offs within 16KB buffer
    const u16* sp[4];
    int sldb[4];
    #pragma unroll
    for (int j = 0; j < 4; ++j) {
        int a, cc;
        if (j < 3) { int c = wv * 3 + j;  a = (c < 8) ? 0 : 1; cc = (c < 8) ? c : (c - 8); }
        else       { a = 2; cc = wv; }
        int row  = cc * 16 + (lane >> 2);
        int gseg = (lane & 3) ^ ((lane >> 3) & 3);
        int rbase = (a == 0) ? brow : bcol;
        sp[j]   = ptrs[a] + (size_t)(rbase + row) * K + gseg * 8;
        sldb[j] = abase[a] + cc * 1024;
    }

    int aro[4], bro[2];
    #pragma unroll
    for (int i = 0; i < 4; ++i) {
        int mr = wm * 64 + i * 16 + l16;
        aro[i] = mr * 64 + ((quad ^ ((mr >> 1) & 3)) * 16);
    }
    #pragma unroll
    for (int i = 0; i < 2; ++i) {
        int nr = wn * 32 + i * 16 + l16;
        bro[i] = nr * 64 + ((quad ^ ((nr >> 1) & 3)) * 16);
    }

    f32x4 acc[4][2] = {};

    auto mmc = [&](bf16x8 (&ah)[4], bf16x8 b0, bf16x8 b1) {
        __builtin_amdgcn_s_setprio(1);
        #pragma unroll
        for (int mi = 0; mi < 4; ++mi) {
            f32x4 c0 = acc[mi][0], c1 = acc[mi][1];
            c0 = MFMA16(ah[mi], b0, c0);
            c1 = MFMA16(ah[mi], b1, c1);
            acc[mi][0] = c0; acc[mi][1] = c1;
        }
        __builtin_amdgcn_s_setprio(0);
    };

    // prologue: issue iter-0 loads in phase order
    #pragma unroll
    for (int j = 0; j < 4; ++j)
        gl16(sp[j], (char*)LB[0] + sldb[j]);

    for (int it = 0; it < K / 32 - 1; ++it) {
        const int cur = it & 1, nx = cur ^ 1;
        const int k1 = (it + 1) * 32;
        bf16x8 ah[4], b0, b1;

        // ---- phase 0 : hi ---- (oldest 3 = this iter's A,Bh chunks)
        asm volatile("s_waitcnt vmcnt(1)" ::: "memory");
        __builtin_amdgcn_s_barrier();
        #pragma unroll
        for (int i = 0; i < 4; ++i)
            ah[i] = *reinterpret_cast<const bf16x8*>((const char*)LB[cur] + aro[i]);
        b0 = *reinterpret_cast<const bf16x8*>((const char*)LB[cur] + 8192 + bro[0]);
        b1 = *reinterpret_cast<const bf16x8*>((const char*)LB[cur] + 8192 + bro[1]);
        gl16(sp[0] + k1, (char*)LB[nx] + sldb[0]);
        gl16(sp[1] + k1, (char*)LB[nx] + sldb[1]);
        gl16(sp[2] + k1, (char*)LB[nx] + sldb[2]);
        mmc(ah, b0, b1);

        // ---- phase 1 : lo ---- (oldest 1 = this iter's Bl chunk)
        asm volatile("s_waitcnt vmcnt(3)" ::: "memory");
        __builtin_amdgcn_s_barrier();
        b0 = *reinterpret_cast<const bf16x8*>((const char*)LB[cur] + 12288 + bro[0]);
        b1 = *reinterpret_cast<const bf16x8*>((const char*)LB[cur] + 12288 + bro[1]);
        gl16(sp[3] + k1, (char*)LB[nx] + sldb[3]);
        mmc(ah, b0, b1);
    }

    // ---- last iteration peeled: no prefetch; exact drain counts ----
    {
        const int cur = (K / 32 - 1) & 1;
        bf16x8 ah[4], b0, b1;

        asm volatile("s_waitcnt vmcnt(1)" ::: "memory");
        __builtin_amdgcn_s_barrier();
        #pragma unroll
        for (int i = 0; i < 4; ++i)
            ah[i] = *reinterpret_cast<const bf16x8*>((const char*)LB[cur] + aro[i]);
        b0 = *reinterpret_cast<const bf16x8*>((const char*)LB[cur] + 8192 + bro[0]);
        b1 = *reinterpret_cast<const bf16x8*>((const char*)LB[cur] + 8192 + bro[1]);
        mmc(ah, b0, b1);

        asm volatile("s_waitcnt vmcnt(0)" ::: "memory");
        __builtin_amdgcn_s_barrier();
        b0 = *reinterpret_cast<const bf16x8*>((const char*)LB[cur] + 12288 + bro[0]);
        b1 = *reinterpret_cast<const bf16x8*>((const char*)LB[cur] + 12288 + bro[1]);
        mmc(ah, b0, b1);
    }

    #pragma unroll
    for (int mi = 0; mi < 4; ++mi) {
        #pragma unroll
        for (int ni = 0; ni < 2; ++ni) {
            int col = bcol + wn * 32 + ni * 16 + l16;
            float bvv = bias[col];
            #pragma unroll
            for (int r = 0; r < 4; ++r) {
                int row = brow + wm * 64 + mi * 16 + quad * 4 + r;
                Cf[(size_t)row * N + col] = acc[mi][ni][r] + bvv;
            }
        }
    }
}

// ---------------------------------------------------------------------------
// V bf16 flat [BH][SEQ][64] -> Vt bf16 [BH][64][SEQ], with k PERMUTED within
// each 64-tile: p(k=16*t4+l) = 4*l + t4. This matches attn's packed-b64 P
// store layout; PV contracts P and V positionally so both sides permute.
// ---------------------------------------------------------------------------
__global__ __launch_bounds__(256) void v_transpose(
    const u16* __restrict__ V, u16* __restrict__ Vt)
{
    __shared__ u16 T[64][72];
    const int bh = blockIdx.y, st = blockIdx.x;
    const u16* src = V + ((size_t)bh * SEQ + (size_t)st * 64) * 64;
    const int t = threadIdx.x;
    #pragma unroll
    for (int i = 0; i < 2; ++i) {
        int c  = t + i * 256;
        int s  = c >> 3;
        int d0 = (c & 7) * 8;
        uint4 v = reinterpret_cast<const uint4*>(src)[c];
        u16 e[8];
        e[0] = (u16)(v.x & 0xffff); e[1] = (u16)(v.x >> 16);
        e[2] = (u16)(v.y & 0xffff); e[3] = (u16)(v.y >> 16);
        e[4] = (u16)(v.z & 0xffff); e[5] = (u16)(v.z >> 16);
        e[6] = (u16)(v.w & 0xffff); e[7] = (u16)(v.w >> 16);
        #pragma unroll
        for (int j = 0; j < 8; ++j) T[d0 + j][s] = e[j];
    }
    __syncthreads();
    // permuted gather: dest positions 8g..8g+7 hold kv
    // [2g, 2g+16, 2g+32, 2g+48, 2g+1, 2g+17, 2g+33, 2g+49]
    const int d = t >> 2, seg = t & 3;
    u16* dst = Vt + (size_t)bh * 64 * SEQ + (size_t)d * SEQ + st * 64;
    #pragma unroll
    for (int gg = 0; gg < 2; ++gg) {
        int g = seg * 2 + gg;
        u32 r0 = *reinterpret_cast<const u32*>(&T[d][2 * g]);
        u32 r1 = *reinterpret_cast<const u32*>(&T[d][2 * g + 16]);
        u32 r2 = *reinterpret_cast<const u32*>(&T[d][2 * g + 32]);
        u32 r3 = *reinterpret_cast<const u32*>(&T[d][2 * g + 48]);
        uint4 w;
        w.x = (r0 & 0xffffu) | (r1 << 16);
        w.y = (r2 & 0xffffu) | (r3 << 16);
        w.z = (r0 >> 16) | (r1 & 0xffff0000u);
        w.w = (r2 >> 16) | (r3 & 0xffff0000u);
        *reinterpret_cast<uint4*>(&dst[8 * g]) = w;
    }
}

// ---------------------------------------------------------------------------
// MFMA flash attention, 512 threads (8 waves x 16 q-rows): 4 waves/SIMD for
// latency hiding. Q pre-scaled -> p = exp2(s); truncated-bf16 P;
// row sums via ones-MFMA on the SAME bf16 P fragments.
// P stored k-PERMUTED (p(16t4+l)=4l+t4) so each thread's 4 exp2 results for
// one row pack into ONE ds_write_b64. V's k order pre-permuted identically.
// T15 PV-lag pipeline (KVS triple-buffered) + T5 setprio.
// LDS 66 KB -> 2 blocks/CU. 1D grid (512), XCD swizzle bh = id&31.
// ---------------------------------------------------------------------------
__global__ __launch_bounds__(512, 4) void attn_mfma(
    const u16* __restrict__ Qb_g, const u16* __restrict__ Kb_g,
    const u16* __restrict__ Vt_g, u16* __restrict__ Ch_g)
{
    __shared__ u16 KVS[3][8192];   // per buf: Kb(8KB) | Vt(8KB)
    __shared__ u16 Pb [128 * 72];

    const int tid  = threadIdx.x;
    const int wv   = tid >> 6;          // 0..7
    const int lane = tid & 63;
    const int quad = lane >> 4;
    const int l16  = lane & 15;
    const int id   = blockIdx.x;
    const int bh   = id & 31;           // XCD = id%8 = bh%8
    const int qt   = id >> 5;           // 0..15
    const int qrow = wv * 16;           // wave's 16 q-rows

    const size_t qbase = ((size_t)bh * SEQ + (size_t)qt * 128) * 64;
    const size_t kbh   = (size_t)bh * SEQ * 64;
    const size_t vtbh  = (size_t)bh * 64 * SEQ;

    // ---- Q fragments: direct global -> VGPR (16 q-rows per wave) ----
    bf16x8 qf[2];
    #pragma unroll
    for (int ks = 0; ks < 2; ++ks) {
        size_t o = qbase + (size_t)(qrow + l16) * 64 + ks * 32 + quad * 8;
        qf[ks] = *reinterpret_cast<const bf16x8*>(Qb_g + o);
    }

    // K/V staging: 16 chunks of 1 KB (Kb 0-7, Vt 8-15); 2 per wave
    const u16* sp[2];
    size_t sstep[2];
    int sldb[2];
    #pragma unroll
    for (int j = 0; j < 2; ++j) {
        int c   = wv * 2 + j;            // 0..15
        int arr = c >> 3, cc = c & 7;
        int row = cc * 8 + (lane >> 3);
        int sg  = (lane & 7) ^ (row & 7);
        if (arr == 0) { sp[j] = Kb_g + kbh + (size_t)row * 64 + sg * 8;   sstep[j] = 4096; }
        else          { sp[j] = Vt_g + vtbh + (size_t)row * SEQ + sg * 8; sstep[j] = 64; }
        sldb[j] = arr * 8192 + cc * 1024;
    }

    int fro[4][2];
    #pragma unroll
    for (int t = 0; t < 4; ++t)
        #pragma unroll
        for (int ks = 0; ks < 2; ++ks)
            fro[t][ks] = (t * 16 + l16) * 128 + (((ks * 4 + quad) ^ (l16 & 7)) * 16);

    bf16x8 onesv;
    #pragma unroll
    for (int i = 0; i < 8; ++i) onesv[i] = (__bf16)1.0f;

    f32x4 oacc[4] = {};
    f32x4 lsum = {};

    // ---- pipeline stage helpers ----
    auto S_step = [&](int bufidx, f32x4 (&sacc)[4]) {
        const char* kb = (const char*)KVS[bufidx];
        #pragma unroll
        for (int t4 = 0; t4 < 4; ++t4) {
            bf16x8 kh0 = *reinterpret_cast<const bf16x8*>(kb + fro[t4][0]);
            bf16x8 kh1 = *reinterpret_cast<const bf16x8*>(kb + fro[t4][1]);
            f32x4 a = sacc[t4];
            a = MFMA16(qf[0], kh0, a);
            a = MFMA16(qf[1], kh1, a);
            sacc[t4] = a;
        }
    };

    auto PV_step = [&](int bufidx) {
        const char* vb = (const char*)KVS[bufidx] + 8192;
        bf16x8 bvf[4][2];
        #pragma unroll
        for (int dt = 0; dt < 4; ++dt) {
            bvf[dt][0] = *reinterpret_cast<const bf16x8*>(vb + fro[dt][0]);
            bvf[dt][1] = *reinterpret_cast<const bf16x8*>(vb + fro[dt][1]);
        }
        bf16x8 ap[2];
        #pragma unroll
        for (int ks = 0; ks < 2; ++ks)
            ap[ks] = *reinterpret_cast<const bf16x8*>(
                &Pb[(qrow + l16) * 72 + ks * 32 + quad * 8]);
        #pragma unroll
        for (int dt = 0; dt < 4; ++dt) {
            oacc[dt] = MFMA16(ap[0], bvf[dt][0], oacc[dt]);
            oacc[dt] = MFMA16(ap[1], bvf[dt][1], oacc[dt]);
        }
        lsum = MFMA16(ap[0], onesv, lsum);
        lsum = MFMA16(ap[1], onesv, lsum);
    };

    auto EXP2_step = [&](f32x4 (&sacc)[4]) {
        const int rowb = qrow + quad * 4;
        #pragma unroll
        for (int r = 0; r < 4; ++r) {
            u32 u0 = __float_as_uint(__builtin_amdgcn_exp2f(sacc[0][r]));
            u32 u1 = __float_as_uint(__builtin_amdgcn_exp2f(sacc[1][r]));
            u32 u2 = __float_as_uint(__builtin_amdgcn_exp2f(sacc[2][r]));
            u32 u3 = __float_as_uint(__builtin_amdgcn_exp2f(sacc[3][r]));
            // permuted pack: elements 4*l16 + {0,1,2,3} = t4 0..3 (truncated bf16)
            uint2 w;
            w.x = (u0 >> 16) | (u1 & 0xffff0000u);
            w.y = (u2 >> 16) | (u3 & 0xffff0000u);
            *reinterpret_cast<uint2*>(&Pb[(rowb + r) * 72 + l16 * 4]) = w;
        }
    };

    // ---- prologue: stage tile 0 ----
    #pragma unroll
    for (int j = 0; j < 2; ++j)
        gl16(sp[j], (char*)KVS[0] + sldb[j]);

    // ---- kt = 0 peeled (no PV yet) ----
    {
        __syncthreads();
        #pragma unroll
        for (int j = 0; j < 2; ++j)
            gl16(sp[j] + sstep[j], (char*)KVS[1] + sldb[j]);
        f32x4 sacc[4] = {};
        __builtin_amdgcn_s_setprio(1);
        S_step(0, sacc);
        __builtin_amdgcn_s_setprio(0);
        EXP2_step(sacc);
    }

    // ---- main loop: S(kt) || PV(kt-1), then exp2(kt) ----
    int cur = 1, prv = 0, nxt = 2;
    for (int kt = 1; kt < SEQ / 64; ++kt) {
        __syncthreads();
        if (kt + 1 < SEQ / 64) {
            #pragma unroll
            for (int j = 0; j < 2; ++j)
                gl16(sp[j] + (size_t)(kt + 1) * sstep[j], (char*)KVS[nxt] + sldb[j]);
        }

        f32x4 sacc[4] = {};
        __builtin_amdgcn_s_setprio(1);
        S_step(cur, sacc);
        PV_step(prv);            // reads Pb(kt-1) BEFORE exp2(kt) overwrites it
        __builtin_amdgcn_s_setprio(0);
        EXP2_step(sacc);

        prv = cur; cur = nxt; nxt = (nxt == 2) ? 0 : nxt + 1;
    }

    // ---- drain: PV on the last tile (V landed at last barrier; Pb same-wave)
    __builtin_amdgcn_s_setprio(1);
    PV_step(prv);                // prv == (SEQ/64 - 1) % 3
    __builtin_amdgcn_s_setprio(0);

    // ---- epilogue: normalize by lsum (C-layout rows match oacc), store ----
    u16* Oh = Ch_g + qbase;
    float inv[4];
    #pragma unroll
    for (int r = 0; r < 4; ++r) inv[r] = 1.0f / lsum[r];
    #pragma unroll
    for (int dt = 0; dt < 4; ++dt)
        #pragma unroll
        for (int r = 0; r < 4; ++r) {
            int row = qrow + quad * 4 + r;
            Oh[(size_t)row * 64 + dt * 16 + l16] = f2bf(oacc[dt][r] * inv[r]);
        }
}

// ---------------------------------------------------------------------------
extern "C" void kernel_launch(void* const* d_in, const int* in_sizes, int n_in,
                              void* d_out, int out_size, void* d_ws, size_t ws_size,
                              hipStream_t stream)
{
    const float* x  = (const float*)d_in[0];
    const float* Wq = (const float*)d_in[1];
    const float* bq = (const float*)d_in[2];
    const float* Wk = (const float*)d_in[3];
    const float* bk = (const float*)d_in[4];
    const float* Wv = (const float*)d_in[5];
    const float* bv = (const float*)d_in[6];
    const float* Wo = (const float*)d_in[7];
    const float* bo = (const float*)d_in[8];
    float* out = (float*)d_out;

    const int M = BATCH * SEQ;        // 4096
    const int N = D_MODEL;            // 1024
    const size_t NE = (size_t)M * N;  // 4,194,304
    const size_t NW = (size_t)N * N;  // 1,048,576

    u16* w16 = (u16*)d_ws;
    u16* Xh   = w16;
    u16* Qb   = Xh   + NE;
    u16* Kb   = Qb   + NE;
    u16* Vb   = Kb   + NE;
    u16* Vtb  = Vb   + NE;
    u16* Ctxh = Vtb  + NE;
    u16* WTqh = Ctxh + NE;
    u16* WTql = WTqh + NW;
    u16* WTkh = WTql + NW;
    u16* WTkl = WTkh + NW;
    u16* WTvh = WTkl + NW;
    u16* WTvl = WTvh + NW;
    u16* WToh = WTvl + NW;
    u16* WTol = WToh + NW;

    // conversions (single launch)
    conv_all<<<dim3(4096 + 1024), dim3(256), 0, stream>>>(
        x, Xh, (int)(NE / 4),
        Wq, Wk, Wv, Wo, WTqh, WTql, WTkh, WTkl, WTvh, WTvl, WToh, WTol);

    // fused QKV projection (128x64 tile, 2 blocks/CU, 3-phase counted-vmcnt)
    gemm_qkv<<<dim3(N / 64, M / 128), dim3(256), 0, stream>>>(
        Xh, WTqh, WTql, WTkh, WTkl, WTvh, WTvl, bq, bk, bv, Qb, Kb, Vb);

    // transpose V per contiguous reshape slab (k permuted to match packed P)
    v_transpose<<<dim3(SEQ / 64, BH), dim3(256), 0, stream>>>(Vb, Vtb);

    // attention (512 threads, 4 waves/SIMD; packed-b64 P; T15 PV-lag)
    attn_mfma<<<dim3((SEQ / 128) * BH), dim3(512), 0, stream>>>(Qb, Kb, Vtb, Ctxh);

    // output projection (128x64 tile, 2 blocks/CU, 2-phase counted-vmcnt)
    gemm_oproj<<<dim3(N / 64, M / 128), dim3(256), 0, stream>>>(
        Ctxh, WToh, WTol, bo, out);
}

// Round 10
// 190.805 us; speedup vs baseline: 1.2303x; 1.0926x over previous
//
#include <hip/hip_runtime.h>
#include <hip/hip_bf16.h>
#include <math.h>

#define D_MODEL 1024
#define SEQ     2048
#define BATCH   2
#define NHEAD   16
#define DKH     64
#define BH      (BATCH * NHEAD)   // 32

typedef unsigned short u16;
typedef unsigned int   u32;
typedef __bf16 bf16x8 __attribute__((ext_vector_type(8)));
typedef float  f32x4  __attribute__((ext_vector_type(4)));

#define MFMA16(a, b, c) __builtin_amdgcn_mfma_f32_16x16x32_bf16((a), (b), (c), 0, 0, 0)
#define AS1 __attribute__((address_space(1)))
#define AS3 __attribute__((address_space(3)))

// 1/(8*ln2): folded into Q so softmax is exp2(s) with no fma and no shift
#define QSCALE 0.18033688f

__device__ __forceinline__ u16 f2bf(float x) {
    u32 u = __float_as_uint(x);
    u += 0x7fffu + ((u >> 16) & 1u);   // RNE (finite data)
    return (u16)(u >> 16);
}
__device__ __forceinline__ float bf2f(u16 b) {
    return __uint_as_float(((u32)b) << 16);
}
// async global->LDS, 16B/lane; lds dest wave-uniform (lane*16 implicit)
__device__ __forceinline__ void gl16(const u16* g, void* lds) {
    __builtin_amdgcn_global_load_lds((const AS1 u32*)g, (AS3 u32*)lds, 16, 0, 0);
}

// ---------------------------------------------------------------------------
// Conversions, one launch:
//   blocks [0, 4096)    : x fp32 -> bf16 (hi only)
//   blocks [4096, 5120) : W [K][N] fp32 -> WT bf16 [N][K]; hi for all 4,
//                         lo ONLY for Wo (bz==3) -- QKV GEMM is single-term
//                         (Q/K/V are bf16-rounded anyway; weight rounding
//                         adds < their existing output-quantization noise).
// ---------------------------------------------------------------------------
__global__ __launch_bounds__(256) void conv_all(
    const float* __restrict__ x, u16* __restrict__ Xh, int n4,
    const float* __restrict__ W0, const float* __restrict__ W1,
    const float* __restrict__ W2, const float* __restrict__ W3,
    u16* __restrict__ H0, u16* __restrict__ L0, u16* __restrict__ H1, u16* __restrict__ L1,
    u16* __restrict__ H2, u16* __restrict__ L2, u16* __restrict__ H3, u16* __restrict__ L3)
{
    const int t = threadIdx.x;
    if ((int)blockIdx.x < 4096) {
        int i = blockIdx.x * 256 + t;
        if (i >= n4) return;
        float4 v = reinterpret_cast<const float4*>(x)[i];
        uint2 H;
        H.x = f2bf(v.x) | ((u32)f2bf(v.y) << 16);
        H.y = f2bf(v.z) | ((u32)f2bf(v.w) << 16);
        reinterpret_cast<uint2*>(Xh)[i] = H;
        return;
    }
    int id = blockIdx.x - 4096;          // 0..1023
    int bx = id & 15, by = (id >> 4) & 15, bz = id >> 8;
    const float* W; u16 *Ht, *Lt;
    if (bz == 0)      { W = W0; Ht = H0; Lt = L0; }
    else if (bz == 1) { W = W1; Ht = H1; Lt = L1; }
    else if (bz == 2) { W = W2; Ht = H2; Lt = L2; }
    else              { W = W3; Ht = H3; Lt = L3; }

    __shared__ float T[64][65];
    const int n0 = bx * 64, k0 = by * 64;
    #pragma unroll
    for (int i = 0; i < 4; ++i) {
        int f = t + i * 256;
        int kr = f >> 4, ns = (f & 15) * 4;
        float4 v = *reinterpret_cast<const float4*>(&W[(size_t)(k0 + kr) * D_MODEL + n0 + ns]);
        T[kr][ns + 0] = v.x; T[kr][ns + 1] = v.y; T[kr][ns + 2] = v.z; T[kr][ns + 3] = v.w;
    }
    __syncthreads();
    #pragma unroll
    for (int i = 0; i < 4; ++i) {
        int f = t + i * 256;
        int nr = f >> 4, ks = (f & 15) * 4;
        u16 hh[4], ll[4];
        #pragma unroll
        for (int j = 0; j < 4; ++j) {
            float xv = T[ks + j][nr];
            u16 hb = f2bf(xv);
            hh[j] = hb;
            ll[j] = f2bf(xv - bf2f(hb));
        }
        uint2 H, L;
        H.x = hh[0] | ((u32)hh[1] << 16); H.y = hh[2] | ((u32)hh[3] << 16);
        L.x = ll[0] | ((u32)ll[1] << 16); L.y = ll[2] | ((u32)ll[3] << 16);
        size_t o = (size_t)(n0 + nr) * D_MODEL + k0 + ks;
        *reinterpret_cast<uint2*>(&Ht[o]) = H;
        if (bz == 3)
            *reinterpret_cast<uint2*>(&Lt[o]) = L;
    }
}

// ---------------------------------------------------------------------------
// Fused QKV GEMM, SINGLE-term: C = Ah @ Bh^T + bias (R10: lo-term dropped;
// Q/K/V outputs are bf16-rounded anyway, weight rounding adds ~sqrt(2)x to
// existing quantization noise -- measured headroom 3.9x).
// 128x64 tile, 256 threads (4 waves, wave tile 64x32); LDS 40KB total.
// 3-phase counted-vmcnt: per wave 5 chunks/iter (ph0: 3 = A+Bqh, ph1: 1 =
// Bkh, ph2: 1 = Bvh); steady waits vmcnt(2)/(4)/(4); peeled last 2/1/0.
// All arrays LDS-staged (R6 lesson). T5 setprio around MFMA clusters.
// Q output pre-scaled by QSCALE (softmax fold). All outputs flat bf16.
// ---------------------------------------------------------------------------
__global__ __launch_bounds__(256, 2) void gemm_qkv(
    const u16* __restrict__ AhG,
    const u16* __restrict__ Bqh, const u16* __restrict__ Bkh, const u16* __restrict__ Bvh,
    const float* __restrict__ bq, const float* __restrict__ bk, const float* __restrict__ bv,
    u16* __restrict__ Qb, u16* __restrict__ Kb, u16* __restrict__ Vb)
{
    constexpr int K = D_MODEL, N = D_MODEL;
    __shared__ u16 LB[2][10240];   // per buf 20KB: A(8KB) | Bqh(4KB) | Bkh(4KB) | Bvh(4KB)

    const int tid  = threadIdx.x;
    const int wv   = tid >> 6;          // 0..3
    const int lane = tid & 63;
    const int quad = lane >> 4;
    const int l16  = lane & 15;
    const int wm   = wv & 1, wn = wv >> 1;   // wave tile 64 rows x 32 cols
    const int brow = blockIdx.y * 128, bcol = blockIdx.x * 64;

    // 5 staging chunks per wave: j=0..2 phase0 (A 8 + Bqh 4), j=3 ph1 (Bkh), j=4 ph2 (Bvh)
    const u16* ptrs[4] = { AhG, Bqh, Bkh, Bvh };
    const int abase[4] = { 0, 8192, 12288, 16384 };   // byte offs, sum = 20KB
    const u16* sp[5];
    int sldb[5];
    #pragma unroll
    for (int j = 0; j < 5; ++j) {
        int a, cc;
        if (j < 3)      { int c = wv * 3 + j; if (c < 8) { a = 0; cc = c; } else { a = 1; cc = c - 8; } }
        else if (j == 3){ a = 2; cc = wv; }
        else            { a = 3; cc = wv; }
        int row  = cc * 16 + (lane >> 2);
        int gseg = (lane & 3) ^ ((lane >> 3) & 3);
        int rbase = (a == 0) ? brow : bcol;
        sp[j]   = ptrs[a] + (size_t)(rbase + row) * K + gseg * 8;
        sldb[j] = abase[a] + cc * 1024;
    }

    int aro[4], bro[2];
    #pragma unroll
    for (int i = 0; i < 4; ++i) {
        int mr = wm * 64 + i * 16 + l16;
        aro[i] = mr * 64 + ((quad ^ ((mr >> 1) & 3)) * 16);
    }
    #pragma unroll
    for (int i = 0; i < 2; ++i) {
        int nr = wn * 32 + i * 16 + l16;
        bro[i] = nr * 64 + ((quad ^ ((nr >> 1) & 3)) * 16);
    }

    f32x4 acc[3][4][2] = {};

    auto mm = [&](int m, bf16x8 (&ah)[4], bf16x8 b0, bf16x8 b1) {
        __builtin_amdgcn_s_setprio(1);
        #pragma unroll
        for (int mi = 0; mi < 4; ++mi) {
            f32x4 c0 = acc[m][mi][0], c1 = acc[m][mi][1];
            c0 = MFMA16(ah[mi], b0, c0);
            c1 = MFMA16(ah[mi], b1, c1);
            acc[m][mi][0] = c0; acc[m][mi][1] = c1;
        }
        __builtin_amdgcn_s_setprio(0);
    };

    // prologue: issue iter-0 loads in phase order (vmcnt counting relies on it)
    #pragma unroll
    for (int j = 0; j < 5; ++j)
        gl16(sp[j], (char*)LB[0] + sldb[j]);

    for (int it = 0; it < K / 32 - 1; ++it) {
        const int cur = it & 1, nx = cur ^ 1;
        const int k1 = (it + 1) * 32;
        bf16x8 ah[4], b0, b1;

        // ---- phase 0 : Q ---- (oldest 3 = this iter's A+Bqh chunks)
        asm volatile("s_waitcnt vmcnt(2)" ::: "memory");
        __builtin_amdgcn_s_barrier();
        #pragma unroll
        for (int i = 0; i < 4; ++i)
            ah[i] = *reinterpret_cast<const bf16x8*>((const char*)LB[cur] + aro[i]);
        b0 = *reinterpret_cast<const bf16x8*>((const char*)LB[cur] + 8192 + bro[0]);
        b1 = *reinterpret_cast<const bf16x8*>((const char*)LB[cur] + 8192 + bro[1]);
        gl16(sp[0] + k1, (char*)LB[nx] + sldb[0]);
        gl16(sp[1] + k1, (char*)LB[nx] + sldb[1]);
        gl16(sp[2] + k1, (char*)LB[nx] + sldb[2]);
        mm(0, ah, b0, b1);

        // ---- phase 1 : K ---- (oldest 1 = this iter's Bkh chunk)
        asm volatile("s_waitcnt vmcnt(4)" ::: "memory");
        __builtin_amdgcn_s_barrier();
        b0 = *reinterpret_cast<const bf16x8*>((const char*)LB[cur] + 12288 + bro[0]);
        b1 = *reinterpret_cast<const bf16x8*>((const char*)LB[cur] + 12288 + bro[1]);
        gl16(sp[3] + k1, (char*)LB[nx] + sldb[3]);
        mm(1, ah, b0, b1);

        // ---- phase 2 : V ---- (oldest 1 = this iter's Bvh chunk)
        asm volatile("s_waitcnt vmcnt(4)" ::: "memory");
        __builtin_amdgcn_s_barrier();
        b0 = *reinterpret_cast<const bf16x8*>((const char*)LB[cur] + 16384 + bro[0]);
        b1 = *reinterpret_cast<const bf16x8*>((const char*)LB[cur] + 16384 + bro[1]);
        gl16(sp[4] + k1, (char*)LB[nx] + sldb[4]);
        mm(2, ah, b0, b1);
    }

    // ---- last iteration peeled: no prefetch; exact drain counts ----
    {
        const int cur = (K / 32 - 1) & 1;
        bf16x8 ah[4], b0, b1;

        asm volatile("s_waitcnt vmcnt(2)" ::: "memory");
        __builtin_amdgcn_s_barrier();
        #pragma unroll
        for (int i = 0; i < 4; ++i)
            ah[i] = *reinterpret_cast<const bf16x8*>((const char*)LB[cur] + aro[i]);
        b0 = *reinterpret_cast<const bf16x8*>((const char*)LB[cur] + 8192 + bro[0]);
        b1 = *reinterpret_cast<const bf16x8*>((const char*)LB[cur] + 8192 + bro[1]);
        mm(0, ah, b0, b1);

        asm volatile("s_waitcnt vmcnt(1)" ::: "memory");
        __builtin_amdgcn_s_barrier();
        b0 = *reinterpret_cast<const bf16x8*>((const char*)LB[cur] + 12288 + bro[0]);
        b1 = *reinterpret_cast<const bf16x8*>((const char*)LB[cur] + 12288 + bro[1]);
        mm(1, ah, b0, b1);

        asm volatile("s_waitcnt vmcnt(0)" ::: "memory");
        __builtin_amdgcn_s_barrier();
        b0 = *reinterpret_cast<const bf16x8*>((const char*)LB[cur] + 16384 + bro[0]);
        b1 = *reinterpret_cast<const bf16x8*>((const char*)LB[cur] + 16384 + bro[1]);
        mm(2, ah, b0, b1);
    }

    // epilogue: Q pre-scaled for exp2-softmax; all flat bf16
    #pragma unroll
    for (int m = 0; m < 3; ++m) {
        const float* bias = (m == 0) ? bq : (m == 1) ? bk : bv;
        u16* out = (m == 0) ? Qb : (m == 1) ? Kb : Vb;
        const float sc = (m == 0) ? QSCALE : 1.0f;
        #pragma unroll
        for (int mi = 0; mi < 4; ++mi) {
            #pragma unroll
            for (int ni = 0; ni < 2; ++ni) {
                int col = bcol + wn * 32 + ni * 16 + l16;
                float bvv = bias[col];
                #pragma unroll
                for (int r = 0; r < 4; ++r) {
                    int row = brow + wm * 64 + mi * 16 + quad * 4 + r;
                    out[(size_t)row * N + col] = f2bf((acc[m][mi][ni][r] + bvv) * sc);
                }
            }
        }
    }
}

// ---------------------------------------------------------------------------
// Out-proj GEMM, 2-term: out = Ctx @ (Woh+Wol)^T + bo, fp32 out.
// (lo-term KEPT here: fp32 output has no masking quantization.)
// 128x64 tile, 256 threads (4 waves), LDS 32KB total.
// 2-phase counted-vmcnt: per wave 4 chunks/iter (ph0: 3 = A+Bh, ph1: 1 = Bl);
// steady waits vmcnt(1)/(3); peeled last iter 1/0.
// ---------------------------------------------------------------------------
__global__ __launch_bounds__(256, 2) void gemm_oproj(
    const u16* __restrict__ AhG, const u16* __restrict__ Bh, const u16* __restrict__ Bl,
    const float* __restrict__ bias, float* __restrict__ Cf)
{
    constexpr int K = D_MODEL, N = D_MODEL;
    __shared__ u16 LB[2][8192];   // per buf 16KB: A(8KB) | Bh(4KB) | Bl(4KB)

    const int tid  = threadIdx.x;
    const int wv   = tid >> 6;          // 0..3
    const int lane = tid & 63;
    const int quad = lane >> 4;
    const int l16  = lane & 15;
    const int wm   = wv & 1, wn = wv >> 1;   // wave tile 64 rows x 32 cols
    const int brow = blockIdx.y * 128, bcol = blockIdx.x * 64;

    // 4 staging chunks per wave: j=0..2 phase0 (A 8 + Bh 4), j=3 phase1 (Bl)
    const u16* ptrs[3] = { AhG, Bh, Bl };
    const int abase[3] = { 0, 8192, 12288 };   // byte offs within 16KB buffer
    const u16* sp[4];
    int sldb[4];
    #pragma unroll
    for (int j = 0; j < 4; ++j) {
        int a, cc;
        if (j < 3) { int c = wv * 3 + j;  a = (c < 8) ? 0 : 1; cc = (c < 8) ? c : (c - 8); }
        else       { a = 2; cc = wv; }
        int row  = cc * 16 + (lane >> 2);
        int gseg = (lane & 3) ^ ((lane >> 3) & 3);
        int rbase = (a == 0) ? brow : bcol;
        sp[j]   = ptrs[a] + (size_t)(rbase + row) * K + gseg * 8;
        sldb[j] = abase[a] + cc * 1024;
    }

    int aro[4], bro[2];
    #pragma unroll
    for (int i = 0; i < 4; ++i) {
        int mr = wm * 64 + i * 16 + l16;
        aro[i] = mr * 64 + ((quad ^ ((mr >> 1) & 3)) * 16);
    }
    #pragma unroll
    for (int i = 0; i < 2; ++i) {
        int nr = wn * 32 + i * 16 + l16;
        bro[i] = nr * 64 + ((quad ^ ((nr >> 1) & 3)) * 16);
    }

    f32x4 acc[4][2] = {};

    auto mmc = [&](bf16x8 (&ah)[4], bf16x8 b0, bf16x8 b1) {
        __builtin_amdgcn_s_setprio(1);
        #pragma unroll
        for (int mi = 0; mi < 4; ++mi) {
            f32x4 c0 = acc[mi][0], c1 = acc[mi][1];
            c0 = MFMA16(ah[mi], b0, c0);
            c1 = MFMA16(ah[mi], b1, c1);
            acc[mi][0] = c0; acc[mi][1] = c1;
        }
        __builtin_amdgcn_s_setprio(0);
    };

    // prologue: issue iter-0 loads in phase order
    #pragma unroll
    for (int j = 0; j < 4; ++j)
        gl16(sp[j], (char*)LB[0] + sldb[j]);

    for (int it = 0; it < K / 32 - 1; ++it) {
        const int cur = it & 1, nx = cur ^ 1;
        const int k1 = (it + 1) * 32;
        bf16x8 ah[4], b0, b1;

        // ---- phase 0 : hi ---- (oldest 3 = this iter's A,Bh chunks)
        asm volatile("s_waitcnt vmcnt(1)" ::: "memory");
        __builtin_amdgcn_s_barrier();
        #pragma unroll
        for (int i = 0; i < 4; ++i)
            ah[i] = *reinterpret_cast<const bf16x8*>((const char*)LB[cur] + aro[i]);
        b0 = *reinterpret_cast<const bf16x8*>((const char*)LB[cur] + 8192 + bro[0]);
        b1 = *reinterpret_cast<const bf16x8*>((const char*)LB[cur] + 8192 + bro[1]);
        gl16(sp[0] + k1, (char*)LB[nx] + sldb[0]);
        gl16(sp[1] + k1, (char*)LB[nx] + sldb[1]);
        gl16(sp[2] + k1, (char*)LB[nx] + sldb[2]);
        mmc(ah, b0, b1);

        // ---- phase 1 : lo ---- (oldest 1 = this iter's Bl chunk)
        asm volatile("s_waitcnt vmcnt(3)" ::: "memory");
        __builtin_amdgcn_s_barrier();
        b0 = *reinterpret_cast<const bf16x8*>((const char*)LB[cur] + 12288 + bro[0]);
        b1 = *reinterpret_cast<const bf16x8*>((const char*)LB[cur] + 12288 + bro[1]);
        gl16(sp[3] + k1, (char*)LB[nx] + sldb[3]);
        mmc(ah, b0, b1);
    }

    // ---- last iteration peeled: no prefetch; exact drain counts ----
    {
        const int cur = (K / 32 - 1) & 1;
        bf16x8 ah[4], b0, b1;

        asm volatile("s_waitcnt vmcnt(1)" ::: "memory");
        __builtin_amdgcn_s_barrier();
        #pragma unroll
        for (int i = 0; i < 4; ++i)
            ah[i] = *reinterpret_cast<const bf16x8*>((const char*)LB[cur] + aro[i]);
        b0 = *reinterpret_cast<const bf16x8*>((const char*)LB[cur] + 8192 + bro[0]);
        b1 = *reinterpret_cast<const bf16x8*>((const char*)LB[cur] + 8192 + bro[1]);
        mmc(ah, b0, b1);

        asm volatile("s_waitcnt vmcnt(0)" ::: "memory");
        __builtin_amdgcn_s_barrier();
        b0 = *reinterpret_cast<const bf16x8*>((const char*)LB[cur] + 12288 + bro[0]);
        b1 = *reinterpret_cast<const bf16x8*>((const char*)LB[cur] + 12288 + bro[1]);
        mmc(ah, b0, b1);
    }

    #pragma unroll
    for (int mi = 0; mi < 4; ++mi) {
        #pragma unroll
        for (int ni = 0; ni < 2; ++ni) {
            int col = bcol + wn * 32 + ni * 16 + l16;
            float bvv = bias[col];
            #pragma unroll
            for (int r = 0; r < 4; ++r) {
                int row = brow + wm * 64 + mi * 16 + quad * 4 + r;
                Cf[(size_t)row * N + col] = acc[mi][ni][r] + bvv;
            }
        }
    }
}

// ---------------------------------------------------------------------------
// V bf16 flat [BH][SEQ][64] -> Vt bf16 [BH][64][SEQ], with k PERMUTED within
// each 64-tile: p(k=16*t4+l) = 4*l + t4. This matches attn's packed-b64 P
// store layout; PV contracts P and V positionally so both sides permute.
// ---------------------------------------------------------------------------
__global__ __launch_bounds__(256) void v_transpose(
    const u16* __restrict__ V, u16* __restrict__ Vt)
{
    __shared__ u16 T[64][72];
    const int bh = blockIdx.y, st = blockIdx.x;
    const u16* src = V + ((size_t)bh * SEQ + (size_t)st * 64) * 64;
    const int t = threadIdx.x;
    #pragma unroll
    for (int i = 0; i < 2; ++i) {
        int c  = t + i * 256;
        int s  = c >> 3;
        int d0 = (c & 7) * 8;
        uint4 v = reinterpret_cast<const uint4*>(src)[c];
        u16 e[8];
        e[0] = (u16)(v.x & 0xffff); e[1] = (u16)(v.x >> 16);
        e[2] = (u16)(v.y & 0xffff); e[3] = (u16)(v.y >> 16);
        e[4] = (u16)(v.z & 0xffff); e[5] = (u16)(v.z >> 16);
        e[6] = (u16)(v.w & 0xffff); e[7] = (u16)(v.w >> 16);
        #pragma unroll
        for (int j = 0; j < 8; ++j) T[d0 + j][s] = e[j];
    }
    __syncthreads();
    // permuted gather: dest positions 8g..8g+7 hold kv
    // [2g, 2g+16, 2g+32, 2g+48, 2g+1, 2g+17, 2g+33, 2g+49]
    const int d = t >> 2, seg = t & 3;
    u16* dst = Vt + (size_t)bh * 64 * SEQ + (size_t)d * SEQ + st * 64;
    #pragma unroll
    for (int gg = 0; gg < 2; ++gg) {
        int g = seg * 2 + gg;
        u32 r0 = *reinterpret_cast<const u32*>(&T[d][2 * g]);
        u32 r1 = *reinterpret_cast<const u32*>(&T[d][2 * g + 16]);
        u32 r2 = *reinterpret_cast<const u32*>(&T[d][2 * g + 32]);
        u32 r3 = *reinterpret_cast<const u32*>(&T[d][2 * g + 48]);
        uint4 w;
        w.x = (r0 & 0xffffu) | (r1 << 16);
        w.y = (r2 & 0xffffu) | (r3 << 16);
        w.z = (r0 >> 16) | (r1 & 0xffff0000u);
        w.w = (r2 >> 16) | (r3 & 0xffff0000u);
        *reinterpret_cast<uint4*>(&dst[8 * g]) = w;
    }
}

// ---------------------------------------------------------------------------
// MFMA flash attention, 512 threads (8 waves x 16 q-rows): 4 waves/SIMD for
// latency hiding. Q pre-scaled -> p = exp2(s); truncated-bf16 P;
// row sums via ones-MFMA on the SAME bf16 P fragments.
// P stored k-PERMUTED (p(16t4+l)=4l+t4) so each thread's 4 exp2 results for
// one row pack into ONE ds_write_b64. V's k order pre-permuted identically.
// T15 PV-lag pipeline (KVS triple-buffered) + T5 setprio.
// LDS 66 KB -> 2 blocks/CU. 1D grid (512), XCD swizzle bh = id&31.
// ---------------------------------------------------------------------------
__global__ __launch_bounds__(512, 4) void attn_mfma(
    const u16* __restrict__ Qb_g, const u16* __restrict__ Kb_g,
    const u16* __restrict__ Vt_g, u16* __restrict__ Ch_g)
{
    __shared__ u16 KVS[3][8192];   // per buf: Kb(8KB) | Vt(8KB)
    __shared__ u16 Pb [128 * 72];

    const int tid  = threadIdx.x;
    const int wv   = tid >> 6;          // 0..7
    const int lane = tid & 63;
    const int quad = lane >> 4;
    const int l16  = lane & 15;
    const int id   = blockIdx.x;
    const int bh   = id & 31;           // XCD = id%8 = bh%8
    const int qt   = id >> 5;           // 0..15
    const int qrow = wv * 16;           // wave's 16 q-rows

    const size_t qbase = ((size_t)bh * SEQ + (size_t)qt * 128) * 64;
    const size_t kbh   = (size_t)bh * SEQ * 64;
    const size_t vtbh  = (size_t)bh * 64 * SEQ;

    // ---- Q fragments: direct global -> VGPR (16 q-rows per wave) ----
    bf16x8 qf[2];
    #pragma unroll
    for (int ks = 0; ks < 2; ++ks) {
        size_t o = qbase + (size_t)(qrow + l16) * 64 + ks * 32 + quad * 8;
        qf[ks] = *reinterpret_cast<const bf16x8*>(Qb_g + o);
    }

    // K/V staging: 16 chunks of 1 KB (Kb 0-7, Vt 8-15); 2 per wave
    const u16* sp[2];
    size_t sstep[2];
    int sldb[2];
    #pragma unroll
    for (int j = 0; j < 2; ++j) {
        int c   = wv * 2 + j;            // 0..15
        int arr = c >> 3, cc = c & 7;
        int row = cc * 8 + (lane >> 3);
        int sg  = (lane & 7) ^ (row & 7);
        if (arr == 0) { sp[j] = Kb_g + kbh + (size_t)row * 64 + sg * 8;   sstep[j] = 4096; }
        else          { sp[j] = Vt_g + vtbh + (size_t)row * SEQ + sg * 8; sstep[j] = 64; }
        sldb[j] = arr * 8192 + cc * 1024;
    }

    int fro[4][2];
    #pragma unroll
    for (int t = 0; t < 4; ++t)
        #pragma unroll
        for (int ks = 0; ks < 2; ++ks)
            fro[t][ks] = (t * 16 + l16) * 128 + (((ks * 4 + quad) ^ (l16 & 7)) * 16);

    bf16x8 onesv;
    #pragma unroll
    for (int i = 0; i < 8; ++i) onesv[i] = (__bf16)1.0f;

    f32x4 oacc[4] = {};
    f32x4 lsum = {};

    // ---- pipeline stage helpers ----
    auto S_step = [&](int bufidx, f32x4 (&sacc)[4]) {
        const char* kb = (const char*)KVS[bufidx];
        #pragma unroll
        for (int t4 = 0; t4 < 4; ++t4) {
            bf16x8 kh0 = *reinterpret_cast<const bf16x8*>(kb + fro[t4][0]);
            bf16x8 kh1 = *reinterpret_cast<const bf16x8*>(kb + fro[t4][1]);
            f32x4 a = sacc[t4];
            a = MFMA16(qf[0], kh0, a);
            a = MFMA16(qf[1], kh1, a);
            sacc[t4] = a;
        }
    };

    auto PV_step = [&](int bufidx) {
        const char* vb = (const char*)KVS[bufidx] + 8192;
        bf16x8 bvf[4][2];
        #pragma unroll
        for (int dt = 0; dt < 4; ++dt) {
            bvf[dt][0] = *reinterpret_cast<const bf16x8*>(vb + fro[dt][0]);
            bvf[dt][1] = *reinterpret_cast<const bf16x8*>(vb + fro[dt][1]);
        }
        bf16x8 ap[2];
        #pragma unroll
        for (int ks = 0; ks < 2; ++ks)
            ap[ks] = *reinterpret_cast<const bf16x8*>(
                &Pb[(qrow + l16) * 72 + ks * 32 + quad * 8]);
        #pragma unroll
        for (int dt = 0; dt < 4; ++dt) {
            oacc[dt] = MFMA16(ap[0], bvf[dt][0], oacc[dt]);
            oacc[dt] = MFMA16(ap[1], bvf[dt][1], oacc[dt]);
        }
        lsum = MFMA16(ap[0], onesv, lsum);
        lsum = MFMA16(ap[1], onesv, lsum);
    };

    auto EXP2_step = [&](f32x4 (&sacc)[4]) {
        const int rowb = qrow + quad * 4;
        #pragma unroll
        for (int r = 0; r < 4; ++r) {
            u32 u0 = __float_as_uint(__builtin_amdgcn_exp2f(sacc[0][r]));
            u32 u1 = __float_as_uint(__builtin_amdgcn_exp2f(sacc[1][r]));
            u32 u2 = __float_as_uint(__builtin_amdgcn_exp2f(sacc[2][r]));
            u32 u3 = __float_as_uint(__builtin_amdgcn_exp2f(sacc[3][r]));
            // permuted pack: elements 4*l16 + {0,1,2,3} = t4 0..3 (truncated bf16)
            uint2 w;
            w.x = (u0 >> 16) | (u1 & 0xffff0000u);
            w.y = (u2 >> 16) | (u3 & 0xffff0000u);
            *reinterpret_cast<uint2*>(&Pb[(rowb + r) * 72 + l16 * 4]) = w;
        }
    };

    // ---- prologue: stage tile 0 ----
    #pragma unroll
    for (int j = 0; j < 2; ++j)
        gl16(sp[j], (char*)KVS[0] + sldb[j]);

    // ---- kt = 0 peeled (no PV yet) ----
    {
        __syncthreads();
        #pragma unroll
        for (int j = 0; j < 2; ++j)
            gl16(sp[j] + sstep[j], (char*)KVS[1] + sldb[j]);
        f32x4 sacc[4] = {};
        __builtin_amdgcn_s_setprio(1);
        S_step(0, sacc);
        __builtin_amdgcn_s_setprio(0);
        EXP2_step(sacc);
    }

    // ---- main loop: S(kt) || PV(kt-1), then exp2(kt) ----
    int cur = 1, prv = 0, nxt = 2;
    for (int kt = 1; kt < SEQ / 64; ++kt) {
        __syncthreads();
        if (kt + 1 < SEQ / 64) {
            #pragma unroll
            for (int j = 0; j < 2; ++j)
                gl16(sp[j] + (size_t)(kt + 1) * sstep[j], (char*)KVS[nxt] + sldb[j]);
        }

        f32x4 sacc[4] = {};
        __builtin_amdgcn_s_setprio(1);
        S_step(cur, sacc);
        PV_step(prv);            // reads Pb(kt-1) BEFORE exp2(kt) overwrites it
        __builtin_amdgcn_s_setprio(0);
        EXP2_step(sacc);

        prv = cur; cur = nxt; nxt = (nxt == 2) ? 0 : nxt + 1;
    }

    // ---- drain: PV on the last tile (V landed at last barrier; Pb same-wave)
    __builtin_amdgcn_s_setprio(1);
    PV_step(prv);                // prv == (SEQ/64 - 1) % 3
    __builtin_amdgcn_s_setprio(0);

    // ---- epilogue: normalize by lsum (C-layout rows match oacc), store ----
    u16* Oh = Ch_g + qbase;
    float inv[4];
    #pragma unroll
    for (int r = 0; r < 4; ++r) inv[r] = 1.0f / lsum[r];
    #pragma unroll
    for (int dt = 0; dt < 4; ++dt)
        #pragma unroll
        for (int r = 0; r < 4; ++r) {
            int row = qrow + quad * 4 + r;
            Oh[(size_t)row * 64 + dt * 16 + l16] = f2bf(oacc[dt][r] * inv[r]);
        }
}

// ---------------------------------------------------------------------------
extern "C" void kernel_launch(void* const* d_in, const int* in_sizes, int n_in,
                              void* d_out, int out_size, void* d_ws, size_t ws_size,
                              hipStream_t stream)
{
    const float* x  = (const float*)d_in[0];
    const float* Wq = (const float*)d_in[1];
    const float* bq = (const float*)d_in[2];
    const float* Wk = (const float*)d_in[3];
    const float* bk = (const float*)d_in[4];
    const float* Wv = (const float*)d_in[5];
    const float* bv = (const float*)d_in[6];
    const float* Wo = (const float*)d_in[7];
    const float* bo = (const float*)d_in[8];
    float* out = (float*)d_out;

    const int M = BATCH * SEQ;        // 4096
    const int N = D_MODEL;            // 1024
    const size_t NE = (size_t)M * N;  // 4,194,304
    const size_t NW = (size_t)N * N;  // 1,048,576

    u16* w16 = (u16*)d_ws;
    u16* Xh   = w16;
    u16* Qb   = Xh   + NE;
    u16* Kb   = Qb   + NE;
    u16* Vb   = Kb   + NE;
    u16* Vtb  = Vb   + NE;
    u16* Ctxh = Vtb  + NE;
    u16* WTqh = Ctxh + NE;
    u16* WTql = WTqh + NW;
    u16* WTkh = WTql + NW;
    u16* WTkl = WTkh + NW;
    u16* WTvh = WTkl + NW;
    u16* WTvl = WTvh + NW;
    u16* WToh = WTvl + NW;
    u16* WTol = WToh + NW;

    // conversions (single launch; lo computed only for Wo)
    conv_all<<<dim3(4096 + 1024), dim3(256), 0, stream>>>(
        x, Xh, (int)(NE / 4),
        Wq, Wk, Wv, Wo, WTqh, WTql, WTkh, WTkl, WTvh, WTvl, WToh, WTol);

    // fused QKV projection (SINGLE-term, 128x64 tile, 3-phase counted-vmcnt)
    gemm_qkv<<<dim3(N / 64, M / 128), dim3(256), 0, stream>>>(
        Xh, WTqh, WTkh, WTvh, bq, bk, bv, Qb, Kb, Vb);

    // transpose V per contiguous reshape slab (k permuted to match packed P)
    v_transpose<<<dim3(SEQ / 64, BH), dim3(256), 0, stream>>>(Vb, Vtb);

    // attention (512 threads, 4 waves/SIMD; packed-b64 P; T15 PV-lag)
    attn_mfma<<<dim3((SEQ / 128) * BH), dim3(512), 0, stream>>>(Qb, Kb, Vtb, Ctxh);

    // output projection (2-term, 128x64 tile, 2-phase counted-vmcnt)
    gemm_oproj<<<dim3(N / 64, M / 128), dim3(256), 0, stream>>>(
        Ctxh, WToh, WTol, bo, out);
}

// Round 11
// 188.720 us; speedup vs baseline: 1.2438x; 1.0110x over previous
//
#include <hip/hip_runtime.h>
#include <hip/hip_bf16.h>
#include <math.h>

#define D_MODEL 1024
#define SEQ     2048
#define BATCH   2
#define NHEAD   16
#define DKH     64
#define BH      (BATCH * NHEAD)   // 32

typedef unsigned short u16;
typedef unsigned int   u32;
typedef __bf16 bf16x8 __attribute__((ext_vector_type(8)));
typedef float  f32x4  __attribute__((ext_vector_type(4)));

#define MFMA16(a, b, c) __builtin_amdgcn_mfma_f32_16x16x32_bf16((a), (b), (c), 0, 0, 0)
#define AS1 __attribute__((address_space(1)))
#define AS3 __attribute__((address_space(3)))

// 1/(8*ln2): folded into Q so softmax is exp2(s) with no fma and no shift
#define QSCALE 0.18033688f

__device__ __forceinline__ u16 f2bf(float x) {
    u32 u = __float_as_uint(x);
    u += 0x7fffu + ((u >> 16) & 1u);   // RNE (finite data)
    return (u16)(u >> 16);
}
__device__ __forceinline__ float bf2f(u16 b) {
    return __uint_as_float(((u32)b) << 16);
}
// async global->LDS, 16B/lane; lds dest wave-uniform (lane*16 implicit)
__device__ __forceinline__ void gl16(const u16* g, void* lds) {
    __builtin_amdgcn_global_load_lds((const AS1 u32*)g, (AS3 u32*)lds, 16, 0, 0);
}

// ---------------------------------------------------------------------------
// Conversions, one launch:
//   blocks [0, 4096)    : x fp32 -> bf16 (hi only)
//   blocks [4096, 5120) : W [K][N] fp32 -> WT bf16 [N][K]; hi for all 4,
//                         lo ONLY for Wo (bz==3).
// ---------------------------------------------------------------------------
__global__ __launch_bounds__(256) void conv_all(
    const float* __restrict__ x, u16* __restrict__ Xh, int n4,
    const float* __restrict__ W0, const float* __restrict__ W1,
    const float* __restrict__ W2, const float* __restrict__ W3,
    u16* __restrict__ H0, u16* __restrict__ L0, u16* __restrict__ H1, u16* __restrict__ L1,
    u16* __restrict__ H2, u16* __restrict__ L2, u16* __restrict__ H3, u16* __restrict__ L3)
{
    const int t = threadIdx.x;
    if ((int)blockIdx.x < 4096) {
        int i = blockIdx.x * 256 + t;
        if (i >= n4) return;
        float4 v = reinterpret_cast<const float4*>(x)[i];
        uint2 H;
        H.x = f2bf(v.x) | ((u32)f2bf(v.y) << 16);
        H.y = f2bf(v.z) | ((u32)f2bf(v.w) << 16);
        reinterpret_cast<uint2*>(Xh)[i] = H;
        return;
    }
    int id = blockIdx.x - 4096;          // 0..1023
    int bx = id & 15, by = (id >> 4) & 15, bz = id >> 8;
    const float* W; u16 *Ht, *Lt;
    if (bz == 0)      { W = W0; Ht = H0; Lt = L0; }
    else if (bz == 1) { W = W1; Ht = H1; Lt = L1; }
    else if (bz == 2) { W = W2; Ht = H2; Lt = L2; }
    else              { W = W3; Ht = H3; Lt = L3; }

    __shared__ float T[64][65];
    const int n0 = bx * 64, k0 = by * 64;
    #pragma unroll
    for (int i = 0; i < 4; ++i) {
        int f = t + i * 256;
        int kr = f >> 4, ns = (f & 15) * 4;
        float4 v = *reinterpret_cast<const float4*>(&W[(size_t)(k0 + kr) * D_MODEL + n0 + ns]);
        T[kr][ns + 0] = v.x; T[kr][ns + 1] = v.y; T[kr][ns + 2] = v.z; T[kr][ns + 3] = v.w;
    }
    __syncthreads();
    #pragma unroll
    for (int i = 0; i < 4; ++i) {
        int f = t + i * 256;
        int nr = f >> 4, ks = (f & 15) * 4;
        u16 hh[4], ll[4];
        #pragma unroll
        for (int j = 0; j < 4; ++j) {
            float xv = T[ks + j][nr];
            u16 hb = f2bf(xv);
            hh[j] = hb;
            ll[j] = f2bf(xv - bf2f(hb));
        }
        uint2 H, L;
        H.x = hh[0] | ((u32)hh[1] << 16); H.y = hh[2] | ((u32)hh[3] << 16);
        L.x = ll[0] | ((u32)ll[1] << 16); L.y = ll[2] | ((u32)ll[3] << 16);
        size_t o = (size_t)(n0 + nr) * D_MODEL + k0 + ks;
        *reinterpret_cast<uint2*>(&Ht[o]) = H;
        if (bz == 3)
            *reinterpret_cast<uint2*>(&Lt[o]) = L;
    }
}

// ---------------------------------------------------------------------------
// Fused QKV GEMM, SINGLE-term: C = Ah @ Bh^T + bias (lo-term dropped; Q/K/V
// outputs are bf16-rounded anyway -- verified absmax 1.46e-3 vs 3.9e-3 thr).
// 128x64 tile, 256 threads (4 waves, wave tile 64x32); LDS 40KB total.
// 3-phase counted-vmcnt: per wave 5 chunks/iter (ph0: 3 = A+Bqh, ph1: 1 =
// Bkh, ph2: 1 = Bvh); steady waits vmcnt(2)/(4)/(4); peeled last 2/1/0.
// ---------------------------------------------------------------------------
__global__ __launch_bounds__(256, 2) void gemm_qkv(
    const u16* __restrict__ AhG,
    const u16* __restrict__ Bqh, const u16* __restrict__ Bkh, const u16* __restrict__ Bvh,
    const float* __restrict__ bq, const float* __restrict__ bk, const float* __restrict__ bv,
    u16* __restrict__ Qb, u16* __restrict__ Kb, u16* __restrict__ Vb)
{
    constexpr int K = D_MODEL, N = D_MODEL;
    __shared__ u16 LB[2][10240];   // per buf 20KB: A(8KB) | Bqh(4KB) | Bkh(4KB) | Bvh(4KB)

    const int tid  = threadIdx.x;
    const int wv   = tid >> 6;          // 0..3
    const int lane = tid & 63;
    const int quad = lane >> 4;
    const int l16  = lane & 15;
    const int wm   = wv & 1, wn = wv >> 1;   // wave tile 64 rows x 32 cols
    const int brow = blockIdx.y * 128, bcol = blockIdx.x * 64;

    // 5 staging chunks per wave: j=0..2 phase0 (A 8 + Bqh 4), j=3 ph1 (Bkh), j=4 ph2 (Bvh)
    const u16* ptrs[4] = { AhG, Bqh, Bkh, Bvh };
    const int abase[4] = { 0, 8192, 12288, 16384 };   // byte offs, sum = 20KB
    const u16* sp[5];
    int sldb[5];
    #pragma unroll
    for (int j = 0; j < 5; ++j) {
        int a, cc;
        if (j < 3)      { int c = wv * 3 + j; if (c < 8) { a = 0; cc = c; } else { a = 1; cc = c - 8; } }
        else if (j == 3){ a = 2; cc = wv; }
        else            { a = 3; cc = wv; }
        int row  = cc * 16 + (lane >> 2);
        int gseg = (lane & 3) ^ ((lane >> 3) & 3);
        int rbase = (a == 0) ? brow : bcol;
        sp[j]   = ptrs[a] + (size_t)(rbase + row) * K + gseg * 8;
        sldb[j] = abase[a] + cc * 1024;
    }

    int aro[4], bro[2];
    #pragma unroll
    for (int i = 0; i < 4; ++i) {
        int mr = wm * 64 + i * 16 + l16;
        aro[i] = mr * 64 + ((quad ^ ((mr >> 1) & 3)) * 16);
    }
    #pragma unroll
    for (int i = 0; i < 2; ++i) {
        int nr = wn * 32 + i * 16 + l16;
        bro[i] = nr * 64 + ((quad ^ ((nr >> 1) & 3)) * 16);
    }

    f32x4 acc[3][4][2] = {};

    auto mm = [&](int m, bf16x8 (&ah)[4], bf16x8 b0, bf16x8 b1) {
        __builtin_amdgcn_s_setprio(1);
        #pragma unroll
        for (int mi = 0; mi < 4; ++mi) {
            f32x4 c0 = acc[m][mi][0], c1 = acc[m][mi][1];
            c0 = MFMA16(ah[mi], b0, c0);
            c1 = MFMA16(ah[mi], b1, c1);
            acc[m][mi][0] = c0; acc[m][mi][1] = c1;
        }
        __builtin_amdgcn_s_setprio(0);
    };

    // prologue: issue iter-0 loads in phase order (vmcnt counting relies on it)
    #pragma unroll
    for (int j = 0; j < 5; ++j)
        gl16(sp[j], (char*)LB[0] + sldb[j]);

    for (int it = 0; it < K / 32 - 1; ++it) {
        const int cur = it & 1, nx = cur ^ 1;
        const int k1 = (it + 1) * 32;
        bf16x8 ah[4], b0, b1;

        // ---- phase 0 : Q ---- (oldest 3 = this iter's A+Bqh chunks)
        asm volatile("s_waitcnt vmcnt(2)" ::: "memory");
        __builtin_amdgcn_s_barrier();
        #pragma unroll
        for (int i = 0; i < 4; ++i)
            ah[i] = *reinterpret_cast<const bf16x8*>((const char*)LB[cur] + aro[i]);
        b0 = *reinterpret_cast<const bf16x8*>((const char*)LB[cur] + 8192 + bro[0]);
        b1 = *reinterpret_cast<const bf16x8*>((const char*)LB[cur] + 8192 + bro[1]);
        gl16(sp[0] + k1, (char*)LB[nx] + sldb[0]);
        gl16(sp[1] + k1, (char*)LB[nx] + sldb[1]);
        gl16(sp[2] + k1, (char*)LB[nx] + sldb[2]);
        mm(0, ah, b0, b1);

        // ---- phase 1 : K ---- (oldest 1 = this iter's Bkh chunk)
        asm volatile("s_waitcnt vmcnt(4)" ::: "memory");
        __builtin_amdgcn_s_barrier();
        b0 = *reinterpret_cast<const bf16x8*>((const char*)LB[cur] + 12288 + bro[0]);
        b1 = *reinterpret_cast<const bf16x8*>((const char*)LB[cur] + 12288 + bro[1]);
        gl16(sp[3] + k1, (char*)LB[nx] + sldb[3]);
        mm(1, ah, b0, b1);

        // ---- phase 2 : V ---- (oldest 1 = this iter's Bvh chunk)
        asm volatile("s_waitcnt vmcnt(4)" ::: "memory");
        __builtin_amdgcn_s_barrier();
        b0 = *reinterpret_cast<const bf16x8*>((const char*)LB[cur] + 16384 + bro[0]);
        b1 = *reinterpret_cast<const bf16x8*>((const char*)LB[cur] + 16384 + bro[1]);
        gl16(sp[4] + k1, (char*)LB[nx] + sldb[4]);
        mm(2, ah, b0, b1);
    }

    // ---- last iteration peeled: no prefetch; exact drain counts ----
    {
        const int cur = (K / 32 - 1) & 1;
        bf16x8 ah[4], b0, b1;

        asm volatile("s_waitcnt vmcnt(2)" ::: "memory");
        __builtin_amdgcn_s_barrier();
        #pragma unroll
        for (int i = 0; i < 4; ++i)
            ah[i] = *reinterpret_cast<const bf16x8*>((const char*)LB[cur] + aro[i]);
        b0 = *reinterpret_cast<const bf16x8*>((const char*)LB[cur] + 8192 + bro[0]);
        b1 = *reinterpret_cast<const bf16x8*>((const char*)LB[cur] + 8192 + bro[1]);
        mm(0, ah, b0, b1);

        asm volatile("s_waitcnt vmcnt(1)" ::: "memory");
        __builtin_amdgcn_s_barrier();
        b0 = *reinterpret_cast<const bf16x8*>((const char*)LB[cur] + 12288 + bro[0]);
        b1 = *reinterpret_cast<const bf16x8*>((const char*)LB[cur] + 12288 + bro[1]);
        mm(1, ah, b0, b1);

        asm volatile("s_waitcnt vmcnt(0)" ::: "memory");
        __builtin_amdgcn_s_barrier();
        b0 = *reinterpret_cast<const bf16x8*>((const char*)LB[cur] + 16384 + bro[0]);
        b1 = *reinterpret_cast<const bf16x8*>((const char*)LB[cur] + 16384 + bro[1]);
        mm(2, ah, b0, b1);
    }

    // epilogue: Q pre-scaled for exp2-softmax; all flat bf16
    #pragma unroll
    for (int m = 0; m < 3; ++m) {
        const float* bias = (m == 0) ? bq : (m == 1) ? bk : bv;
        u16* out = (m == 0) ? Qb : (m == 1) ? Kb : Vb;
        const float sc = (m == 0) ? QSCALE : 1.0f;
        #pragma unroll
        for (int mi = 0; mi < 4; ++mi) {
            #pragma unroll
            for (int ni = 0; ni < 2; ++ni) {
                int col = bcol + wn * 32 + ni * 16 + l16;
                float bvv = bias[col];
                #pragma unroll
                for (int r = 0; r < 4; ++r) {
                    int row = brow + wm * 64 + mi * 16 + quad * 4 + r;
                    out[(size_t)row * N + col] = f2bf((acc[m][mi][ni][r] + bvv) * sc);
                }
            }
        }
    }
}

// ---------------------------------------------------------------------------
// Out-proj GEMM, 2-term: out = Ctx @ (Woh+Wol)^T + bo, fp32 out.
// 128x64 tile, 256 threads (4 waves), LDS 32KB total.
// 2-phase counted-vmcnt: ph0: 3 = A+Bh, ph1: 1 = Bl; waits 1/3; peel 1/0.
// ---------------------------------------------------------------------------
__global__ __launch_bounds__(256, 2) void gemm_oproj(
    const u16* __restrict__ AhG, const u16* __restrict__ Bh, const u16* __restrict__ Bl,
    const float* __restrict__ bias, float* __restrict__ Cf)
{
    constexpr int K = D_MODEL, N = D_MODEL;
    __shared__ u16 LB[2][8192];   // per buf 16KB: A(8KB) | Bh(4KB) | Bl(4KB)

    const int tid  = threadIdx.x;
    const int wv   = tid >> 6;          // 0..3
    const int lane = tid & 63;
    const int quad = lane >> 4;
    const int l16  = lane & 15;
    const int wm   = wv & 1, wn = wv >> 1;   // wave tile 64 rows x 32 cols
    const int brow = blockIdx.y * 128, bcol = blockIdx.x * 64;

    // 4 staging chunks per wave: j=0..2 phase0 (A 8 + Bh 4), j=3 phase1 (Bl)
    const u16* ptrs[3] = { AhG, Bh, Bl };
    const int abase[3] = { 0, 8192, 12288 };   // byte offs within 16KB buffer
    const u16* sp[4];
    int sldb[4];
    #pragma unroll
    for (int j = 0; j < 4; ++j) {
        int a, cc;
        if (j < 3) { int c = wv * 3 + j;  a = (c < 8) ? 0 : 1; cc = (c < 8) ? c : (c - 8); }
        else       { a = 2; cc = wv; }
        int row  = cc * 16 + (lane >> 2);
        int gseg = (lane & 3) ^ ((lane >> 3) & 3);
        int rbase = (a == 0) ? brow : bcol;
        sp[j]   = ptrs[a] + (size_t)(rbase + row) * K + gseg * 8;
        sldb[j] = abase[a] + cc * 1024;
    }

    int aro[4], bro[2];
    #pragma unroll
    for (int i = 0; i < 4; ++i) {
        int mr = wm * 64 + i * 16 + l16;
        aro[i] = mr * 64 + ((quad ^ ((mr >> 1) & 3)) * 16);
    }
    #pragma unroll
    for (int i = 0; i < 2; ++i) {
        int nr = wn * 32 + i * 16 + l16;
        bro[i] = nr * 64 + ((quad ^ ((nr >> 1) & 3)) * 16);
    }

    f32x4 acc[4][2] = {};

    auto mmc = [&](bf16x8 (&ah)[4], bf16x8 b0, bf16x8 b1) {
        __builtin_amdgcn_s_setprio(1);
        #pragma unroll
        for (int mi = 0; mi < 4; ++mi) {
            f32x4 c0 = acc[mi][0], c1 = acc[mi][1];
            c0 = MFMA16(ah[mi], b0, c0);
            c1 = MFMA16(ah[mi], b1, c1);
            acc[mi][0] = c0; acc[mi][1] = c1;
        }
        __builtin_amdgcn_s_setprio(0);
    };

    // prologue: issue iter-0 loads in phase order
    #pragma unroll
    for (int j = 0; j < 4; ++j)
        gl16(sp[j], (char*)LB[0] + sldb[j]);

    for (int it = 0; it < K / 32 - 1; ++it) {
        const int cur = it & 1, nx = cur ^ 1;
        const int k1 = (it + 1) * 32;
        bf16x8 ah[4], b0, b1;

        // ---- phase 0 : hi ---- (oldest 3 = this iter's A,Bh chunks)
        asm volatile("s_waitcnt vmcnt(1)" ::: "memory");
        __builtin_amdgcn_s_barrier();
        #pragma unroll
        for (int i = 0; i < 4; ++i)
            ah[i] = *reinterpret_cast<const bf16x8*>((const char*)LB[cur] + aro[i]);
        b0 = *reinterpret_cast<const bf16x8*>((const char*)LB[cur] + 8192 + bro[0]);
        b1 = *reinterpret_cast<const bf16x8*>((const char*)LB[cur] + 8192 + bro[1]);
        gl16(sp[0] + k1, (char*)LB[nx] + sldb[0]);
        gl16(sp[1] + k1, (char*)LB[nx] + sldb[1]);
        gl16(sp[2] + k1, (char*)LB[nx] + sldb[2]);
        mmc(ah, b0, b1);

        // ---- phase 1 : lo ---- (oldest 1 = this iter's Bl chunk)
        asm volatile("s_waitcnt vmcnt(3)" ::: "memory");
        __builtin_amdgcn_s_barrier();
        b0 = *reinterpret_cast<const bf16x8*>((const char*)LB[cur] + 12288 + bro[0]);
        b1 = *reinterpret_cast<const bf16x8*>((const char*)LB[cur] + 12288 + bro[1]);
        gl16(sp[3] + k1, (char*)LB[nx] + sldb[3]);
        mmc(ah, b0, b1);
    }

    // ---- last iteration peeled: no prefetch; exact drain counts ----
    {
        const int cur = (K / 32 - 1) & 1;
        bf16x8 ah[4], b0, b1;

        asm volatile("s_waitcnt vmcnt(1)" ::: "memory");
        __builtin_amdgcn_s_barrier();
        #pragma unroll
        for (int i = 0; i < 4; ++i)
            ah[i] = *reinterpret_cast<const bf16x8*>((const char*)LB[cur] + aro[i]);
        b0 = *reinterpret_cast<const bf16x8*>((const char*)LB[cur] + 8192 + bro[0]);
        b1 = *reinterpret_cast<const bf16x8*>((const char*)LB[cur] + 8192 + bro[1]);
        mmc(ah, b0, b1);

        asm volatile("s_waitcnt vmcnt(0)" ::: "memory");
        __builtin_amdgcn_s_barrier();
        b0 = *reinterpret_cast<const bf16x8*>((const char*)LB[cur] + 12288 + bro[0]);
        b1 = *reinterpret_cast<const bf16x8*>((const char*)LB[cur] + 12288 + bro[1]);
        mmc(ah, b0, b1);
    }

    #pragma unroll
    for (int mi = 0; mi < 4; ++mi) {
        #pragma unroll
        for (int ni = 0; ni < 2; ++ni) {
            int col = bcol + wn * 32 + ni * 16 + l16;
            float bvv = bias[col];
            #pragma unroll
            for (int r = 0; r < 4; ++r) {
                int row = brow + wm * 64 + mi * 16 + quad * 4 + r;
                Cf[(size_t)row * N + col] = acc[mi][ni][r] + bvv;
            }
        }
    }
}

// ---------------------------------------------------------------------------
// V bf16 flat [BH][SEQ][64] -> Vt bf16 [BH][64][SEQ], with k PERMUTED within
// each 64-tile: p(k=16*t4+l) = 4*l + t4. Matches attn's packed-b64 P layout.
// ---------------------------------------------------------------------------
__global__ __launch_bounds__(256) void v_transpose(
    const u16* __restrict__ V, u16* __restrict__ Vt)
{
    __shared__ u16 T[64][72];
    const int bh = blockIdx.y, st = blockIdx.x;
    const u16* src = V + ((size_t)bh * SEQ + (size_t)st * 64) * 64;
    const int t = threadIdx.x;
    #pragma unroll
    for (int i = 0; i < 2; ++i) {
        int c  = t + i * 256;
        int s  = c >> 3;
        int d0 = (c & 7) * 8;
        uint4 v = reinterpret_cast<const uint4*>(src)[c];
        u16 e[8];
        e[0] = (u16)(v.x & 0xffff); e[1] = (u16)(v.x >> 16);
        e[2] = (u16)(v.y & 0xffff); e[3] = (u16)(v.y >> 16);
        e[4] = (u16)(v.z & 0xffff); e[5] = (u16)(v.z >> 16);
        e[6] = (u16)(v.w & 0xffff); e[7] = (u16)(v.w >> 16);
        #pragma unroll
        for (int j = 0; j < 8; ++j) T[d0 + j][s] = e[j];
    }
    __syncthreads();
    // permuted gather: dest positions 8g..8g+7 hold kv
    // [2g, 2g+16, 2g+32, 2g+48, 2g+1, 2g+17, 2g+33, 2g+49]
    const int d = t >> 2, seg = t & 3;
    u16* dst = Vt + (size_t)bh * 64 * SEQ + (size_t)d * SEQ + st * 64;
    #pragma unroll
    for (int gg = 0; gg < 2; ++gg) {
        int g = seg * 2 + gg;
        u32 r0 = *reinterpret_cast<const u32*>(&T[d][2 * g]);
        u32 r1 = *reinterpret_cast<const u32*>(&T[d][2 * g + 16]);
        u32 r2 = *reinterpret_cast<const u32*>(&T[d][2 * g + 32]);
        u32 r3 = *reinterpret_cast<const u32*>(&T[d][2 * g + 48]);
        uint4 w;
        w.x = (r0 & 0xffffu) | (r1 << 16);
        w.y = (r2 & 0xffffu) | (r3 << 16);
        w.z = (r0 >> 16) | (r1 & 0xffff0000u);
        w.w = (r2 >> 16) | (r3 & 0xffff0000u);
        *reinterpret_cast<uint4*>(&dst[8 * g]) = w;
    }
}

// ---------------------------------------------------------------------------
// MFMA flash attention, R11: 256 threads, 4 waves x 32 q-rows (2x16-row
// sub-tiles) -- K/V fragments read ONCE per 32 rows (halves the per-CU LDS
// read duplication vs 8x16). Keeps R4+ wins: packed-b64 permuted P store
// (V k-permuted to match), T15 PV-lag (KVS triple-buffered), T5 setprio.
// Q pre-scaled -> p = exp2(s); lsum via ones-MFMA on same P fragments.
// LDS 66KB -> 2 blocks/CU. 1D grid (512), XCD swizzle bh = id&31.
// ---------------------------------------------------------------------------
__global__ __launch_bounds__(256, 2) void attn_mfma(
    const u16* __restrict__ Qb_g, const u16* __restrict__ Kb_g,
    const u16* __restrict__ Vt_g, u16* __restrict__ Ch_g)
{
    __shared__ u16 KVS[3][8192];   // per buf: Kb(8KB) | Vt(8KB)
    __shared__ u16 Pb [128 * 72];

    const int tid  = threadIdx.x;
    const int wv   = tid >> 6;          // 0..3
    const int lane = tid & 63;
    const int quad = lane >> 4;
    const int l16  = lane & 15;
    const int id   = blockIdx.x;
    const int bh   = id & 31;           // XCD = id%8 = bh%8
    const int qt   = id >> 5;           // 0..15
    const int qrow = wv * 32;           // wave's 32 q-rows (2 sub-tiles of 16)

    const size_t qbase = ((size_t)bh * SEQ + (size_t)qt * 128) * 64;
    const size_t kbh   = (size_t)bh * SEQ * 64;
    const size_t vtbh  = (size_t)bh * 64 * SEQ;

    // ---- Q fragments: direct global -> VGPR (32 q-rows per wave) ----
    bf16x8 qf[2][2];
    #pragma unroll
    for (int sub = 0; sub < 2; ++sub)
        #pragma unroll
        for (int ks = 0; ks < 2; ++ks) {
            size_t o = qbase + (size_t)(qrow + sub * 16 + l16) * 64 + ks * 32 + quad * 8;
            qf[sub][ks] = *reinterpret_cast<const bf16x8*>(Qb_g + o);
        }

    // K/V staging: 16 chunks of 1 KB (Kb 0-7, Vt 8-15); 4 per wave
    const u16* sp[4];
    size_t sstep[4];
    int sldb[4];
    #pragma unroll
    for (int j = 0; j < 4; ++j) {
        int c   = wv * 4 + j;            // 0..15
        int arr = c >> 3, cc = c & 7;
        int row = cc * 8 + (lane >> 3);
        int sg  = (lane & 7) ^ (row & 7);
        if (arr == 0) { sp[j] = Kb_g + kbh + (size_t)row * 64 + sg * 8;   sstep[j] = 4096; }
        else          { sp[j] = Vt_g + vtbh + (size_t)row * SEQ + sg * 8; sstep[j] = 64; }
        sldb[j] = arr * 8192 + cc * 1024;
    }

    int fro[4][2];
    #pragma unroll
    for (int t = 0; t < 4; ++t)
        #pragma unroll
        for (int ks = 0; ks < 2; ++ks)
            fro[t][ks] = (t * 16 + l16) * 128 + (((ks * 4 + quad) ^ (l16 & 7)) * 16);

    bf16x8 onesv;
    #pragma unroll
    for (int i = 0; i < 8; ++i) onesv[i] = (__bf16)1.0f;

    f32x4 oacc[2][4] = {};
    f32x4 lsum[2] = {};

    // ---- pipeline stage helpers ----
    auto S_step = [&](int bufidx, f32x4 (&sacc)[2][4]) {
        const char* kb = (const char*)KVS[bufidx];
        #pragma unroll
        for (int t4 = 0; t4 < 4; ++t4) {
            bf16x8 kh0 = *reinterpret_cast<const bf16x8*>(kb + fro[t4][0]);
            bf16x8 kh1 = *reinterpret_cast<const bf16x8*>(kb + fro[t4][1]);
            #pragma unroll
            for (int sub = 0; sub < 2; ++sub) {
                f32x4 a = sacc[sub][t4];
                a = MFMA16(qf[sub][0], kh0, a);
                a = MFMA16(qf[sub][1], kh1, a);
                sacc[sub][t4] = a;
            }
        }
    };

    auto PV_step = [&](int bufidx) {
        const char* vb = (const char*)KVS[bufidx] + 8192;
        bf16x8 bvf[4][2];
        #pragma unroll
        for (int dt = 0; dt < 4; ++dt) {
            bvf[dt][0] = *reinterpret_cast<const bf16x8*>(vb + fro[dt][0]);
            bvf[dt][1] = *reinterpret_cast<const bf16x8*>(vb + fro[dt][1]);
        }
        #pragma unroll
        for (int sub = 0; sub < 2; ++sub) {
            bf16x8 ap[2];
            #pragma unroll
            for (int ks = 0; ks < 2; ++ks)
                ap[ks] = *reinterpret_cast<const bf16x8*>(
                    &Pb[(qrow + sub * 16 + l16) * 72 + ks * 32 + quad * 8]);
            #pragma unroll
            for (int dt = 0; dt < 4; ++dt) {
                oacc[sub][dt] = MFMA16(ap[0], bvf[dt][0], oacc[sub][dt]);
                oacc[sub][dt] = MFMA16(ap[1], bvf[dt][1], oacc[sub][dt]);
            }
            lsum[sub] = MFMA16(ap[0], onesv, lsum[sub]);
            lsum[sub] = MFMA16(ap[1], onesv, lsum[sub]);
        }
    };

    auto EXP2_step = [&](f32x4 (&sacc)[2][4]) {
        #pragma unroll
        for (int sub = 0; sub < 2; ++sub) {
            const int rowb = qrow + sub * 16 + quad * 4;
            #pragma unroll
            for (int r = 0; r < 4; ++r) {
                u32 u0 = __float_as_uint(__builtin_amdgcn_exp2f(sacc[sub][0][r]));
                u32 u1 = __float_as_uint(__builtin_amdgcn_exp2f(sacc[sub][1][r]));
                u32 u2 = __float_as_uint(__builtin_amdgcn_exp2f(sacc[sub][2][r]));
                u32 u3 = __float_as_uint(__builtin_amdgcn_exp2f(sacc[sub][3][r]));
                // permuted pack: elements 4*l16 + {0,1,2,3} = t4 0..3 (truncated bf16)
                uint2 w;
                w.x = (u0 >> 16) | (u1 & 0xffff0000u);
                w.y = (u2 >> 16) | (u3 & 0xffff0000u);
                *reinterpret_cast<uint2*>(&Pb[(rowb + r) * 72 + l16 * 4]) = w;
            }
        }
    };

    // ---- prologue: stage tile 0 ----
    #pragma unroll
    for (int j = 0; j < 4; ++j)
        gl16(sp[j], (char*)KVS[0] + sldb[j]);

    // ---- kt = 0 peeled (no PV yet) ----
    {
        __syncthreads();
        #pragma unroll
        for (int j = 0; j < 4; ++j)
            gl16(sp[j] + sstep[j], (char*)KVS[1] + sldb[j]);
        f32x4 sacc[2][4] = {};
        __builtin_amdgcn_s_setprio(1);
        S_step(0, sacc);
        __builtin_amdgcn_s_setprio(0);
        EXP2_step(sacc);
    }

    // ---- main loop: S(kt) || PV(kt-1), then exp2(kt) ----
    int cur = 1, prv = 0, nxt = 2;
    for (int kt = 1; kt < SEQ / 64; ++kt) {
        __syncthreads();
        if (kt + 1 < SEQ / 64) {
            #pragma unroll
            for (int j = 0; j < 4; ++j)
                gl16(sp[j] + (size_t)(kt + 1) * sstep[j], (char*)KVS[nxt] + sldb[j]);
        }

        f32x4 sacc[2][4] = {};
        __builtin_amdgcn_s_setprio(1);
        S_step(cur, sacc);
        PV_step(prv);            // reads Pb(kt-1) BEFORE exp2(kt) overwrites it
        __builtin_amdgcn_s_setprio(0);
        EXP2_step(sacc);

        prv = cur; cur = nxt; nxt = (nxt == 2) ? 0 : nxt + 1;
    }

    // ---- drain: PV on the last tile (V landed at last barrier; Pb same-wave)
    __builtin_amdgcn_s_setprio(1);
    PV_step(prv);                // prv == (SEQ/64 - 1) % 3
    __builtin_amdgcn_s_setprio(0);

    // ---- epilogue: normalize by lsum (C-layout rows match oacc), store ----
    u16* Oh = Ch_g + qbase;
    #pragma unroll
    for (int sub = 0; sub < 2; ++sub) {
        float inv[4];
        #pragma unroll
        for (int r = 0; r < 4; ++r) inv[r] = 1.0f / lsum[sub][r];
        #pragma unroll
        for (int dt = 0; dt < 4; ++dt)
            #pragma unroll
            for (int r = 0; r < 4; ++r) {
                int row = qrow + sub * 16 + quad * 4 + r;
                Oh[(size_t)row * 64 + dt * 16 + l16] = f2bf(oacc[sub][dt][r] * inv[r]);
            }
    }
}

// ---------------------------------------------------------------------------
extern "C" void kernel_launch(void* const* d_in, const int* in_sizes, int n_in,
                              void* d_out, int out_size, void* d_ws, size_t ws_size,
                              hipStream_t stream)
{
    const float* x  = (const float*)d_in[0];
    const float* Wq = (const float*)d_in[1];
    const float* bq = (const float*)d_in[2];
    const float* Wk = (const float*)d_in[3];
    const float* bk = (const float*)d_in[4];
    const float* Wv = (const float*)d_in[5];
    const float* bv = (const float*)d_in[6];
    const float* Wo = (const float*)d_in[7];
    const float* bo = (const float*)d_in[8];
    float* out = (float*)d_out;

    const int M = BATCH * SEQ;        // 4096
    const int N = D_MODEL;            // 1024
    const size_t NE = (size_t)M * N;  // 4,194,304
    const size_t NW = (size_t)N * N;  // 1,048,576

    u16* w16 = (u16*)d_ws;
    u16* Xh   = w16;
    u16* Qb   = Xh   + NE;
    u16* Kb   = Qb   + NE;
    u16* Vb   = Kb   + NE;
    u16* Vtb  = Vb   + NE;
    u16* Ctxh = Vtb  + NE;
    u16* WTqh = Ctxh + NE;
    u16* WTql = WTqh + NW;
    u16* WTkh = WTql + NW;
    u16* WTkl = WTkh + NW;
    u16* WTvh = WTkl + NW;
    u16* WTvl = WTvh + NW;
    u16* WToh = WTvl + NW;
    u16* WTol = WToh + NW;

    // conversions (single launch; lo computed only for Wo)
    conv_all<<<dim3(4096 + 1024), dim3(256), 0, stream>>>(
        x, Xh, (int)(NE / 4),
        Wq, Wk, Wv, Wo, WTqh, WTql, WTkh, WTkl, WTvh, WTvl, WToh, WTol);

    // fused QKV projection (SINGLE-term, 128x64 tile, 3-phase counted-vmcnt)
    gemm_qkv<<<dim3(N / 64, M / 128), dim3(256), 0, stream>>>(
        Xh, WTqh, WTkh, WTvh, bq, bk, bv, Qb, Kb, Vb);

    // transpose V per contiguous reshape slab (k permuted to match packed P)
    v_transpose<<<dim3(SEQ / 64, BH), dim3(256), 0, stream>>>(Vb, Vtb);

    // attention (256 threads, 4 waves x 32 q-rows; packed-b64 P; T15 PV-lag)
    attn_mfma<<<dim3((SEQ / 128) * BH), dim3(256), 0, stream>>>(Qb, Kb, Vtb, Ctxh);

    // output projection (2-term, 128x64 tile, 2-phase counted-vmcnt)
    gemm_oproj<<<dim3(N / 64, M / 128), dim3(256), 0, stream>>>(
        Ctxh, WToh, WTol, bo, out);
}